// Round 3
// baseline (497.299 us; speedup 1.0000x reference)
//
#include <hip/hip_runtime.h>
#include <hip/hip_bf16.h>
#include <stdint.h>

typedef __bf16 bf16x8 __attribute__((ext_vector_type(8)));
typedef float  f32x4  __attribute__((ext_vector_type(4)));

// packed fp32x2 -> bf16x2 (RNE) -- lowers to v_cvt_pk_bf16_f32 on gfx950
__device__ __forceinline__ uint32_t cvt2(float a, float b) {
    __hip_bfloat162 h = __float22bfloat162_rn(make_float2(a, b));
    uint32_t u; __builtin_memcpy(&u, &h, 4); return u;
}
__device__ __forceinline__ float bflo(uint32_t u) { uint32_t t = u << 16;         float f; __builtin_memcpy(&f, &t, 4); return f; }
__device__ __forceinline__ float bfhi(uint32_t u) { uint32_t t = u & 0xffff0000u; float f; __builtin_memcpy(&f, &t, 4); return f; }
__device__ __forceinline__ int swz(int u) { return u ^ ((u >> 3) & 7); }

// async global -> LDS DMA, 16 B/lane. LDS dest must be wave-uniform base + lane*16.
__device__ __forceinline__ void gload_lds16(const void* g, void* l) {
    __builtin_amdgcn_global_load_lds(
        (const __attribute__((address_space(1))) uint32_t*)g,
        (__attribute__((address_space(3))) uint32_t*)l,
        16, 0, 0);
}

// ============================================================================
// Kernel 1: pack x (and W) to bf16 in MFMA-fragment-ready transposed layouts.
//   xT[b][s][l][j] : k = s*8+j (s=0..31), l=0..511  -> B-frag = b128 at (b,s,col)
//   wT[og][s][r][j]: r<32 -> W1 row og*32+r, r>=32 -> W2 row og*32+r-32
// b == id (mod 8): written on the XCD that edge_gemm reads it from. All 16
// x-loads issued before the convert/store phase for max VMEM in flight.
// (measured ~38 us, close to its 30 us traffic floor -- leave alone)
// ============================================================================
__global__ __launch_bounds__(256, 4)
void pack_transpose(const float* __restrict__ x, const float* __restrict__ W,
                    unsigned short* __restrict__ xT, unsigned short* __restrict__ wT)
{
    const int tid = threadIdx.x;
    const int id  = blockIdx.x;
    if (id < 2048) {
        const int b  = ((id >> 6) << 3) + (id & 7);      // XCD-matched: b % 8 == id % 8
        const int kc = (id >> 3) & 7;
        const int s2 = tid >> 6, l4 = tid & 63;          // slab-in-chunk, l-quad
        const float* src0 = x + ((size_t)b << 17) + ((size_t)((kc << 5) + (s2 << 3)) << 9);
        unsigned short* dst0 = xT + (((size_t)(b << 5) + (kc << 2) + s2) << 12);
        f32x4 xr[16];
        #pragma unroll
        for (int lh = 0; lh < 2; ++lh) {
            const int l0 = (lh << 8) + (l4 << 2);
            #pragma unroll
            for (int j = 0; j < 8; ++j)
                xr[(lh << 3) + j] = __builtin_nontemporal_load((const f32x4*)(src0 + (j << 9) + l0));
        }
        #pragma unroll
        for (int lh = 0; lh < 2; ++lh) {
            const int l0 = (lh << 8) + (l4 << 2);
            #pragma unroll
            for (int lv = 0; lv < 4; ++lv) {
                uint4 p;
                p.x = cvt2(xr[(lh << 3) + 0][lv], xr[(lh << 3) + 1][lv]);
                p.y = cvt2(xr[(lh << 3) + 2][lv], xr[(lh << 3) + 3][lv]);
                p.z = cvt2(xr[(lh << 3) + 4][lv], xr[(lh << 3) + 5][lv]);
                p.w = cvt2(xr[(lh << 3) + 6][lv], xr[(lh << 3) + 7][lv]);
                *(uint4*)(dst0 + ((l0 + lv) << 3)) = p;  // 16B/lane, 64B stride; 4 instrs fill
            }
        }
    } else {
        const int og = id - 2048;
        const int r = tid & 63, sg = tid >> 6;
        const float* wrow = W + ((size_t)((og << 5) + (r & 31)) << 9) + ((r >> 5) << 8);
        #pragma unroll
        for (int ss = 0; ss < 8; ++ss) {
            const int s = (sg << 3) + ss;
            float4 f0 = *(const float4*)(wrow + (s << 3));
            float4 f1 = *(const float4*)(wrow + (s << 3) + 4);
            uint4 p;
            p.x = cvt2(f0.x, f0.y); p.y = cvt2(f0.z, f0.w);
            p.z = cvt2(f1.x, f1.y); p.w = cvt2(f1.z, f1.w);
            *(uint4*)(wT + (((((og << 5) + s) << 6) + r) << 3)) = p;
        }
    }
}

// ============================================================================
// Kernel 2: og-pair GEMM. Block = (b, ogp): 512 threads / 8 waves; waves 0-3
// compute og=2*ogp, waves 4-7 og=2*ogp+1, SHARING one staged B chunk.
//  -> 16 waves/CU (4/SIMD, 2x round-2) for latency hiding, and each xT slab
//     is read by 4 blocks instead of 8 (B traffic halved).
// K-loop = round-1 known-good 2-phase: issue next-chunk DMA, ds_read + MFMA
// current, one __syncthreads (compiler-managed vmcnt drain). No asm pins
// (round-2 counted-vmcnt + sched_barrier regressed 82->110 us).
// LDS: 2 x (32KB B + 8KB A) = 80 KB staging; epilogue overlays it with two
// stride-38 (bank-conflict-free) y2 arrays. Chunk kc -> buf[(kc+1)&1].
// ============================================================================
__global__ __launch_bounds__(512, 4)
void edge_gemm(const unsigned short* __restrict__ xT,
               const unsigned short* __restrict__ wT,
               const int* __restrict__ idx,
               float* __restrict__ out)
{
    // staging: buf s at smem + s*40960 : B [32768 B] then A [8192 B]
    // epilogue: y2_a @0 (38912 B), red_a @38912 (1024 B),
    //           y2_b @40960 (38912 B), red_b @79872 (1024 B)
    __shared__ __align__(16) unsigned char smem[81920];

    const int tid  = threadIdx.x;
    const int wv   = tid >> 6;
    const int lane = tid & 63;
    const int m    = lane & 15;
    const int q    = lane >> 4;
    const int g    = wv >> 2;        // og within pair
    const int wsub = wv & 3;         // col-quarter owner within og group

    // id map: 1024 blocks; b % 8 == id % 8 (XCD-local xT reuse), 4 ogp per b
    const int id  = blockIdx.x;
    const int rem = id & 31;
    const int b   = ((id >> 5) << 3) + (rem & 7);
    const int ogp = rem >> 3;
    const int og  = (ogp << 1) + g;
    const int o0  = og << 5;

    const char* xb = (const char*)xT + ((size_t)b << 18);     // b * 256 KB
    const char* wp = (const char*)wT + ((size_t)og << 15);    // og * 32 KB

    unsigned short* y2  = (unsigned short*)(smem + g * 40960);
    float*          red = (float*)(smem + g * 40960 + 38912);

    int iv[8];
    #pragma unroll
    for (int nt = 0; nt < 8; ++nt)
        iv[nt] = idx[((size_t)b << 9) + (wsub << 7) + (nt << 4) + m];

    f32x4 acc[4][8];
    #pragma unroll
    for (int mt = 0; mt < 4; ++mt)
        #pragma unroll
        for (int nt = 0; nt < 8; ++nt)
            acc[mt][nt] = (f32x4){0.f, 0.f, 0.f, 0.f};

    // per-thread staging offsets (LDS dest = wave-uniform base + lane*16)
    const int offB = tid << 4;                               // 512 thr x 16 B = 8 KB / slice
    const int offA = (g << 12) + (wsub << 10) + (lane << 4); // 8 KB A area, per-wave 1 KB

    auto stage = [&](int c, int bsel) {
        char* base = (char*)smem + bsel * 40960;
        const char* Bg = xb + ((size_t)c << 15);
        #pragma unroll
        for (int i = 0; i < 4; ++i)
            gload_lds16(Bg + (i << 13) + offB, base + (i << 13) + offB);
        gload_lds16(wp + (c << 12) + (wsub << 10) + (lane << 4), base + 32768 + offA);
    };

    // ---- prologue: chunk 0 -> buf 1 ----
    stage(0, 1);
    __syncthreads();

    // ---- K loop: issue next-chunk DMA, compute current, one barrier ----
    #pragma unroll
    for (int kc = 0; kc < 8; ++kc) {
        const int bsel = (kc + 1) & 1;                       // chunk kc's buffer
        if (kc < 7) stage(kc + 1, bsel ^ 1);

        const unsigned short* B0 = (const unsigned short*)((const char*)smem + bsel * 40960);
        const unsigned short* A0 = B0 + 16384;               // +32768 bytes
        bf16x8 av[4], bv[8];
        #pragma unroll
        for (int mt = 0; mt < 4; ++mt)
            av[mt] = *(const bf16x8*)(A0 + (g << 11) + (q << 9) + (((mt << 4) + m) << 3));
        #pragma unroll
        for (int nt = 0; nt < 8; ++nt)
            bv[nt] = *(const bf16x8*)(B0 + (q << 12) + (((wsub << 7) + (nt << 4) + m) << 3));
        #pragma unroll
        for (int mt = 0; mt < 4; ++mt)
            #pragma unroll
            for (int nt = 0; nt < 8; ++nt)
                acc[mt][nt] = __builtin_amdgcn_mfma_f32_16x16x32_bf16(av[mt], bv[nt], acc[mt][nt], 0, 0, 0);

        if (kc < 7) __syncthreads();
    }

    // ---- epilogue ----
    __syncthreads();   // all ds_reads of buf0 done before y2_a overlays it

    #pragma unroll
    for (int mt = 2; mt < 4; ++mt)
        #pragma unroll
        for (int nt = 0; nt < 8; ++nt) {
            int col  = (wsub << 7) + (nt << 4) + m;
            int row0 = ((mt - 2) << 4) + (q << 2);
            uint2 p;
            p.x = cvt2(acc[mt][nt][0], acc[mt][nt][1]);
            p.y = cvt2(acc[mt][nt][2], acc[mt][nt][3]);
            *(uint2*)(y2 + col * 38 + row0) = p;
        }
    __syncthreads();

    float vvl[2][8][4];
    float s_[2][4], q_[2][4];
    #pragma unroll
    for (int mt = 0; mt < 2; ++mt)
        #pragma unroll
        for (int r4 = 0; r4 < 4; ++r4) { s_[mt][r4] = 0.f; q_[mt][r4] = 0.f; }

    #pragma unroll
    for (int nt = 0; nt < 8; ++nt) {
        int  c   = iv[nt];
        bool inb = (c < 512);                    // idx==512 -> pad column (zero)
        int  cc  = inb ? c : 0;
        #pragma unroll
        for (int mt = 0; mt < 2; ++mt) {
            uint2 gg = *(const uint2*)(y2 + cc * 38 + (mt << 4) + (q << 2));
            float gv[4];
            gv[0] = inb ? bflo(gg.x) : 0.f;
            gv[1] = inb ? bfhi(gg.x) : 0.f;
            gv[2] = inb ? bflo(gg.y) : 0.f;
            gv[3] = inb ? bfhi(gg.y) : 0.f;
            #pragma unroll
            for (int r4 = 0; r4 < 4; ++r4) {
                float val = acc[mt][nt][r4] + gv[r4];
                vvl[mt][nt][r4] = val;
                s_[mt][r4] += val;
                q_[mt][r4] += val * val;
            }
        }
    }

    // reduce: 16-lane butterfly over m, cross-wave (within og group) via red
    #pragma unroll
    for (int mt = 0; mt < 2; ++mt)
        #pragma unroll
        for (int r4 = 0; r4 < 4; ++r4) {
            float s = s_[mt][r4], ss = q_[mt][r4];
            #pragma unroll
            for (int off = 1; off < 16; off <<= 1) {
                s  += __shfl_xor(s,  off, 64);
                ss += __shfl_xor(ss, off, 64);
            }
            if (m == 0) {
                int r = (mt << 4) + (q << 2) + r4;
                red[(r << 3) + (wsub << 1)]     = s;
                red[(r << 3) + (wsub << 1) + 1] = ss;
            }
        }
    __syncthreads();

    #pragma unroll
    for (int mt = 0; mt < 2; ++mt)
        #pragma unroll
        for (int r4 = 0; r4 < 4; ++r4) {
            int r = (mt << 4) + (q << 2) + r4;
            float S = red[(r << 3)]     + red[(r << 3) + 2] + red[(r << 3) + 4] + red[(r << 3) + 6];
            float Q = red[(r << 3) + 1] + red[(r << 3) + 3] + red[(r << 3) + 5] + red[(r << 3) + 7];
            float mu  = S * (1.0f / 512.0f);
            float var = Q * (1.0f / 512.0f) - mu * mu;
            float rs  = rsqrtf(var + 1e-5f);
            float* op = out + (((size_t)(b << 8) + o0 + r) << 9) + (wsub << 7) + m;
            #pragma unroll
            for (int nt = 0; nt < 8; ++nt) {
                float t = (vvl[mt][nt][r4] - mu) * rs;
                op[nt << 4] = fmaxf(t, 0.0f);
            }
        }
}

// ============================================================================
// Fallback (ws too small): round-2 fused single kernel, unchanged.
// ============================================================================
__global__ __launch_bounds__(256, 2)
void edgeconv_fused(const float* __restrict__ x,
                    const int*   __restrict__ idx,
                    const float* __restrict__ W,
                    float*       __restrict__ out)
{
    __shared__ __align__(16) unsigned char smem[65536];
    unsigned short* wlds = (unsigned short*)smem;
    unsigned short* xTl  = (unsigned short*)(smem + 32768);
    unsigned short* y2   = (unsigned short*)smem;
    float*          red  = (float*)(smem + 38912);

    const int tid  = threadIdx.x;
    const int wv   = tid >> 6;
    const int lane = tid & 63;
    const int m    = lane & 15;
    const int q    = lane >> 4;

    const int id  = blockIdx.x;
    const int rem = id & 63;
    const int b   = ((id >> 6) << 3) + (rem & 7);
    const int o0  = (rem >> 3) << 5;

    const float* xb = x + ((size_t)b << 17);

    #pragma unroll
    for (int i = 0; i < 16; ++i) {
        int r = (i << 2) + wv;
        const float4 f = *(const float4*)(W + ((size_t)(o0 + (r & 31)) << 9)
                                            + ((r >> 5) << 8) + (lane << 2));
        uint2 p; p.x = cvt2(f.x, f.y); p.y = cvt2(f.z, f.w);
        int sl = lane >> 1;
        *(uint2*)(wlds + (sl << 9) + ((swz(r) ^ (sl & 7)) << 3) + ((lane & 1) << 2)) = p;
    }

    f32x4 acc[4][8];
    #pragma unroll
    for (int mt = 0; mt < 4; ++mt)
        #pragma unroll
        for (int nt = 0; nt < 8; ++nt)
            acc[mt][nt] = (f32x4){0.f, 0.f, 0.f, 0.f};

    float4 xr0[8], xr1[8];
    auto loadg = [&](int kc, int g, float4* xr) {
        int gid = (g << 8) + tid;
        int s2  = gid >> 7;
        int l4  = gid & 127;
        const float* base = xb + ((size_t)((kc << 5) + (s2 << 3)) << 9) + (l4 << 2);
        #pragma unroll
        for (int j = 0; j < 8; ++j) xr[j] = *(const float4*)(base + (j << 9));
    };
    auto storeg = [&](int g, const float4* xr) {
        int gid = (g << 8) + tid;
        int s2  = gid >> 7;
        int l4  = gid & 127;
        #pragma unroll
        for (int lv = 0; lv < 4; ++lv) {
            int l = (l4 << 2) + lv;
            uint4 p;
            p.x = cvt2((&xr[0].x)[lv], (&xr[1].x)[lv]);
            p.y = cvt2((&xr[2].x)[lv], (&xr[3].x)[lv]);
            p.z = cvt2((&xr[4].x)[lv], (&xr[5].x)[lv]);
            p.w = cvt2((&xr[6].x)[lv], (&xr[7].x)[lv]);
            *(uint4*)(xTl + (s2 << 12) + (swz(l) << 3)) = p;
        }
    };

    loadg(0, 0, xr0);
    loadg(0, 1, xr1);
    storeg(0, xr0);
    storeg(1, xr1);
    __syncthreads();

    for (int kc = 0; kc < 8; ++kc) {
        if (kc < 7) loadg(kc + 1, 0, xr0);

        bf16x8 av[4], bv[8];
        #pragma unroll
        for (int mt = 0; mt < 4; ++mt) {
            int sl = (kc << 2) + q;
            av[mt] = *(const bf16x8*)(wlds + (sl << 9) + ((swz((mt << 4) + m) ^ (sl & 7)) << 3));
        }
        #pragma unroll
        for (int nt = 0; nt < 8; ++nt)
            bv[nt] = *(const bf16x8*)(xTl + (q << 12) + (swz((wv << 7) + (nt << 4) + m) << 3));

        #pragma unroll
        for (int mt = 0; mt < 4; ++mt)
            #pragma unroll
            for (int nt = 0; nt < 8; ++nt)
                acc[mt][nt] = __builtin_amdgcn_mfma_f32_16x16x32_bf16(av[mt], bv[nt], acc[mt][nt], 0, 0, 0);

        if (kc < 7) loadg(kc + 1, 1, xr1);
        __syncthreads();
        if (kc < 7) {
            storeg(0, xr0);
            storeg(1, xr1);
            __syncthreads();
        }
    }

    int iv[8];
    #pragma unroll
    for (int nt = 0; nt < 8; ++nt)
        iv[nt] = idx[((size_t)b << 9) + (wv << 7) + (nt << 4) + m];

    #pragma unroll
    for (int mt = 2; mt < 4; ++mt)
        #pragma unroll
        for (int nt = 0; nt < 8; ++nt) {
            int col  = (wv << 7) + (nt << 4) + m;
            int row0 = ((mt - 2) << 4) + (q << 2);
            uint2 p;
            p.x = cvt2(acc[mt][nt][0], acc[mt][nt][1]);
            p.y = cvt2(acc[mt][nt][2], acc[mt][nt][3]);
            *(uint2*)(y2 + col * 36 + row0) = p;
        }
    __syncthreads();

    float vvl[2][8][4];
    float s_[2][4], q_[2][4];
    #pragma unroll
    for (int mt = 0; mt < 2; ++mt)
        #pragma unroll
        for (int r4 = 0; r4 < 4; ++r4) { s_[mt][r4] = 0.f; q_[mt][r4] = 0.f; }

    #pragma unroll
    for (int nt = 0; nt < 8; ++nt) {
        int  c   = iv[nt];
        bool inb = (c < 512);
        int  cc  = inb ? c : 0;
        #pragma unroll
        for (int mt = 0; mt < 2; ++mt) {
            uint2 g = *(const uint2*)(y2 + cc * 36 + (mt << 4) + (q << 2));
            float gv[4];
            gv[0] = inb ? bflo(g.x) : 0.f;
            gv[1] = inb ? bfhi(g.x) : 0.f;
            gv[2] = inb ? bflo(g.y) : 0.f;
            gv[3] = inb ? bfhi(g.y) : 0.f;
            #pragma unroll
            for (int r4 = 0; r4 < 4; ++r4) {
                float val = acc[mt][nt][r4] + gv[r4];
                vvl[mt][nt][r4] = val;
                s_[mt][r4] += val;
                q_[mt][r4] += val * val;
            }
        }
    }

    #pragma unroll
    for (int mt = 0; mt < 2; ++mt)
        #pragma unroll
        for (int r4 = 0; r4 < 4; ++r4) {
            float s = s_[mt][r4], ss = q_[mt][r4];
            #pragma unroll
            for (int off = 1; off < 16; off <<= 1) {
                s  += __shfl_xor(s,  off, 64);
                ss += __shfl_xor(ss, off, 64);
            }
            if (m == 0) {
                int r = (mt << 4) + (q << 2) + r4;
                red[(r << 3) + (wv << 1)]     = s;
                red[(r << 3) + (wv << 1) + 1] = ss;
            }
        }
    __syncthreads();

    #pragma unroll
    for (int mt = 0; mt < 2; ++mt)
        #pragma unroll
        for (int r4 = 0; r4 < 4; ++r4) {
            int r = (mt << 4) + (q << 2) + r4;
            float S = red[(r << 3)]     + red[(r << 3) + 2] + red[(r << 3) + 4] + red[(r << 3) + 6];
            float Q = red[(r << 3) + 1] + red[(r << 3) + 3] + red[(r << 3) + 5] + red[(r << 3) + 7];
            float mu  = S * (1.0f / 512.0f);
            float var = Q * (1.0f / 512.0f) - mu * mu;
            float rs  = rsqrtf(var + 1e-5f);
            float* op = out + (((size_t)(b << 8) + o0 + r) << 9) + (wv << 7) + m;
            #pragma unroll
            for (int nt = 0; nt < 8; ++nt) {
                float t = (vvl[mt][nt][r4] - mu) * rs;
                op[nt << 4] = fmaxf(t, 0.0f);
            }
        }
}

extern "C" void kernel_launch(void* const* d_in, const int* in_sizes, int n_in,
                              void* d_out, int out_size, void* d_ws, size_t ws_size,
                              hipStream_t stream) {
    const float* x   = (const float*)d_in[0];   // [256,256,512] fp32
    const int*   idx = (const int*)  d_in[1];   // [256,512] int32, 512 == pad
    const float* W   = (const float*)d_in[2];   // [256,512] fp32
    // d_in[3] (bias) unused: constant-over-L shift cancels in InstanceNorm.
    float* out = (float*)d_out;                 // [256,256,512] fp32

    const size_t xT_bytes = (size_t)256 * 32 * 512 * 8 * 2;   // 67,108,864
    const size_t wT_bytes = (size_t)8 * 32 * 64 * 8 * 2;      // 262,144

    if (ws_size >= xT_bytes + wT_bytes) {
        unsigned short* xT = (unsigned short*)d_ws;
        unsigned short* wT = (unsigned short*)((char*)d_ws + xT_bytes);
        pack_transpose<<<dim3(2056), dim3(256), 0, stream>>>(x, W, xT, wT);
        edge_gemm<<<dim3(1024), dim3(512), 0, stream>>>(xT, wT, idx, out);
    } else {
        edgeconv_fused<<<dim3(2048), dim3(256), 0, stream>>>(x, idx, W, out);
    }
}

// Round 4
// 327.662 us; speedup vs baseline: 1.5177x; 1.5177x over previous
//
#include <hip/hip_runtime.h>
#include <hip/hip_bf16.h>
#include <stdint.h>

typedef __bf16 bf16x8 __attribute__((ext_vector_type(8)));
typedef float  f32x4  __attribute__((ext_vector_type(4)));

// packed fp32x2 -> bf16x2 (RNE) -- lowers to v_cvt_pk_bf16_f32 on gfx950
__device__ __forceinline__ uint32_t cvt2(float a, float b) {
    __hip_bfloat162 h = __float22bfloat162_rn(make_float2(a, b));
    uint32_t u; __builtin_memcpy(&u, &h, 4); return u;
}
__device__ __forceinline__ float bflo(uint32_t u) { uint32_t t = u << 16;         float f; __builtin_memcpy(&f, &t, 4); return f; }
__device__ __forceinline__ float bfhi(uint32_t u) { uint32_t t = u & 0xffff0000u; float f; __builtin_memcpy(&f, &t, 4); return f; }
__device__ __forceinline__ int swz(int u) { return u ^ ((u >> 3) & 7); }

// async global -> LDS DMA, 16 B/lane. LDS dest must be wave-uniform base + lane*16.
__device__ __forceinline__ void gload_lds16(const void* g, void* l) {
    __builtin_amdgcn_global_load_lds(
        (const __attribute__((address_space(1))) uint32_t*)g,
        (__attribute__((address_space(3))) uint32_t*)l,
        16, 0, 0);
}

// ============================================================================
// Kernel 1: pack x (and W) to bf16 in MFMA-fragment-ready transposed layouts.
//   xT[b][s][l][j] : k = s*8+j (s=0..31), l=0..511  -> B-frag = b128 at (b,s,col)
//   wT[og][s][r][j]: r<32 -> W1 row og*32+r, r>=32 -> W2 row og*32+r-32
// b == id (mod 8): written on the XCD that edge_gemm reads it from.
// (measured ~38 us, close to its ~30 us traffic floor -- unchanged)
// ============================================================================
__global__ __launch_bounds__(256, 4)
void pack_transpose(const float* __restrict__ x, const float* __restrict__ W,
                    unsigned short* __restrict__ xT, unsigned short* __restrict__ wT)
{
    const int tid = threadIdx.x;
    const int id  = blockIdx.x;
    if (id < 2048) {
        const int b  = ((id >> 6) << 3) + (id & 7);      // XCD-matched: b % 8 == id % 8
        const int kc = (id >> 3) & 7;
        const int s2 = tid >> 6, l4 = tid & 63;          // slab-in-chunk, l-quad
        const float* src0 = x + ((size_t)b << 17) + ((size_t)((kc << 5) + (s2 << 3)) << 9);
        unsigned short* dst0 = xT + (((size_t)(b << 5) + (kc << 2) + s2) << 12);
        f32x4 xr[16];
        #pragma unroll
        for (int lh = 0; lh < 2; ++lh) {
            const int l0 = (lh << 8) + (l4 << 2);
            #pragma unroll
            for (int j = 0; j < 8; ++j)
                xr[(lh << 3) + j] = __builtin_nontemporal_load((const f32x4*)(src0 + (j << 9) + l0));
        }
        #pragma unroll
        for (int lh = 0; lh < 2; ++lh) {
            const int l0 = (lh << 8) + (l4 << 2);
            #pragma unroll
            for (int lv = 0; lv < 4; ++lv) {
                uint4 p;
                p.x = cvt2(xr[(lh << 3) + 0][lv], xr[(lh << 3) + 1][lv]);
                p.y = cvt2(xr[(lh << 3) + 2][lv], xr[(lh << 3) + 3][lv]);
                p.z = cvt2(xr[(lh << 3) + 4][lv], xr[(lh << 3) + 5][lv]);
                p.w = cvt2(xr[(lh << 3) + 6][lv], xr[(lh << 3) + 7][lv]);
                *(uint4*)(dst0 + ((l0 + lv) << 3)) = p;  // 16B/lane, 64B stride; 4 instrs fill
            }
        }
    } else {
        const int og = id - 2048;
        const int r = tid & 63, sg = tid >> 6;
        const float* wrow = W + ((size_t)((og << 5) + (r & 31)) << 9) + ((r >> 5) << 8);
        #pragma unroll
        for (int ss = 0; ss < 8; ++ss) {
            const int s = (sg << 3) + ss;
            float4 f0 = *(const float4*)(wrow + (s << 3));
            float4 f1 = *(const float4*)(wrow + (s << 3) + 4);
            uint4 p;
            p.x = cvt2(f0.x, f0.y); p.y = cvt2(f0.z, f0.w);
            p.z = cvt2(f1.x, f1.y); p.w = cvt2(f1.z, f1.w);
            *(uint4*)(wT + (((((og << 5) + s) << 6) + r) << 3)) = p;
        }
    }
}

// ============================================================================
// Kernel 2: GEMM, block = (b, og) as round 0/1, but 512 threads / 8 waves:
// wave wv owns 64 columns [wv*64, wv*64+64) -> acc[4][4] = 64 AGPR/wave.
// Epilogue avoids the vvl register cache by RE-READING the y2 gather (holds
// only mu/rs[2][4]) -> unified regs/wave ~110-125, fits the 128 budget of
// __launch_bounds__(512,4). LDS 73728 (2 x 36864 staging) -> 2 blocks/CU =
// 16 waves/CU (4/SIMD), 2x round-1 occupancy. Round-3 spill lesson: if
// WRITE_SIZE balloons past ~131 MB, registers didn't fit.
// K-loop = round-1 known-good 2-phase (no asm pins; round-2 counted-vmcnt
// regressed). Chunk kc -> buf[kc&1].
// ============================================================================
__global__ __launch_bounds__(512, 4)
void edge_gemm(const unsigned short* __restrict__ xT,
               const unsigned short* __restrict__ wT,
               const int* __restrict__ idx,
               float* __restrict__ out)
{
    // staging: buf s at smem + s*36864 : B [32768 B] then A [4096 B]
    // epilogue overlay: y2 bf16 [512 col][38] @0 (38912 B), red @40960 (2 KB)
    __shared__ __align__(16) unsigned char smem[73728];
    unsigned short* y2  = (unsigned short*)smem;
    float*          red = (float*)(smem + 40960);        // fp32 [32 r][8 wv][2]

    const int tid  = threadIdx.x;
    const int wv   = tid >> 6;
    const int lane = tid & 63;
    const int m    = lane & 15;
    const int q    = lane >> 4;

    // XCD swizzle: 8 o-blocks of one b are 8 ids apart -> same XCD round-robin
    const int id  = blockIdx.x;
    const int rem = id & 63;
    const int b   = ((id >> 6) << 3) + (rem & 7);
    const int og  = rem >> 3;
    const int o0  = og << 5;

    const char* xb = (const char*)xT + ((size_t)b << 18); // b * 256 KB
    const char* wb = (const char*)wT + (og << 15);        // og * 32 KB

    int iv[4];
    #pragma unroll
    for (int nt = 0; nt < 4; ++nt)
        iv[nt] = idx[((size_t)b << 9) + (wv << 6) + (nt << 4) + m];

    f32x4 acc[4][4];
    #pragma unroll
    for (int mt = 0; mt < 4; ++mt)
        #pragma unroll
        for (int nt = 0; nt < 4; ++nt)
            acc[mt][nt] = (f32x4){0.f, 0.f, 0.f, 0.f};

    // staging offsets: 512 thr x 16 B = 8 KB per issue; B = 4 issues, A = 1
    const int offB = tid << 4;
    auto stage = [&](int c, int bsel) {
        char* base = (char*)smem + bsel * 36864;
        const char* Bg = xb + ((size_t)c << 15);
        #pragma unroll
        for (int i = 0; i < 4; ++i)
            gload_lds16(Bg + (i << 13) + offB, base + (i << 13) + offB);
        if (tid < 256)
            gload_lds16(wb + (c << 12) + offB, base + 32768 + offB);
    };

    // ---- prologue: chunk 0 -> buf 0 ----
    stage(0, 0);
    __syncthreads();

    // ---- K loop: issue next-chunk DMA, compute current, one barrier ----
    #pragma unroll
    for (int kc = 0; kc < 8; ++kc) {
        const int bsel = kc & 1;
        if (kc < 7) stage(kc + 1, bsel ^ 1);

        const unsigned short* B0 = (const unsigned short*)((const char*)smem + bsel * 36864);
        const unsigned short* A0 = B0 + 16384;            // +32768 bytes
        bf16x8 av[4], bv[4];
        #pragma unroll
        for (int mt = 0; mt < 4; ++mt)
            av[mt] = *(const bf16x8*)(A0 + (q << 9) + (((mt << 4) + m) << 3));
        #pragma unroll
        for (int nt = 0; nt < 4; ++nt)
            bv[nt] = *(const bf16x8*)(B0 + (q << 12) + (((wv << 6) + (nt << 4) + m) << 3));
        #pragma unroll
        for (int mt = 0; mt < 4; ++mt)
            #pragma unroll
            for (int nt = 0; nt < 4; ++nt)
                acc[mt][nt] = __builtin_amdgcn_mfma_f32_16x16x32_bf16(av[mt], bv[nt], acc[mt][nt], 0, 0, 0);

        if (kc < 7) __syncthreads();
    }

    // ---- epilogue: Y2 -> y2 (stride 38: 19 coprime 32, conflict-free) ----
    __syncthreads();   // kc=7 ds_reads (buf1) done before y2 overlays smem

    #pragma unroll
    for (int mt = 2; mt < 4; ++mt)
        #pragma unroll
        for (int nt = 0; nt < 4; ++nt) {
            int col  = (wv << 6) + (nt << 4) + m;
            int row0 = ((mt - 2) << 4) + (q << 2);
            uint2 p;
            p.x = cvt2(acc[mt][nt][0], acc[mt][nt][1]);
            p.y = cvt2(acc[mt][nt][2], acc[mt][nt][3]);
            *(uint2*)(y2 + col * 38 + row0) = p;
        }
    __syncthreads();

    // ---- pass 1: sum / sumsq over this wave's 64 cols (no vvl cache) ----
    float s_[2][4], q_[2][4];
    #pragma unroll
    for (int mt = 0; mt < 2; ++mt)
        #pragma unroll
        for (int r4 = 0; r4 < 4; ++r4) { s_[mt][r4] = 0.f; q_[mt][r4] = 0.f; }

    #pragma unroll
    for (int nt = 0; nt < 4; ++nt) {
        int  c   = iv[nt];
        bool inb = (c < 512);                    // idx==512 -> pad column (zero)
        int  cc  = inb ? c : 0;
        #pragma unroll
        for (int mt = 0; mt < 2; ++mt) {
            uint2 g = *(const uint2*)(y2 + cc * 38 + (mt << 4) + (q << 2));
            float gv[4];
            gv[0] = inb ? bflo(g.x) : 0.f;
            gv[1] = inb ? bfhi(g.x) : 0.f;
            gv[2] = inb ? bflo(g.y) : 0.f;
            gv[3] = inb ? bfhi(g.y) : 0.f;
            #pragma unroll
            for (int r4 = 0; r4 < 4; ++r4) {
                float val = acc[mt][nt][r4] + gv[r4];
                s_[mt][r4] += val;
                q_[mt][r4] += val * val;
            }
        }
    }

    // reduce: 16-lane butterfly over m, cross-wave (8 waves) via red
    #pragma unroll
    for (int mt = 0; mt < 2; ++mt)
        #pragma unroll
        for (int r4 = 0; r4 < 4; ++r4) {
            float s = s_[mt][r4], ss = q_[mt][r4];
            #pragma unroll
            for (int off = 1; off < 16; off <<= 1) {
                s  += __shfl_xor(s,  off, 64);
                ss += __shfl_xor(ss, off, 64);
            }
            if (m == 0) {
                int r = (mt << 4) + (q << 2) + r4;
                red[(r << 4) + (wv << 1)]     = s;
                red[(r << 4) + (wv << 1) + 1] = ss;
            }
        }
    __syncthreads();

    float mu[2][4], rs[2][4];
    #pragma unroll
    for (int mt = 0; mt < 2; ++mt)
        #pragma unroll
        for (int r4 = 0; r4 < 4; ++r4) {
            int r = (mt << 4) + (q << 2) + r4;
            float S = 0.f, Q = 0.f;
            #pragma unroll
            for (int w = 0; w < 8; ++w) {
                S += red[(r << 4) + (w << 1)];
                Q += red[(r << 4) + (w << 1) + 1];
            }
            float muv = S * (1.0f / 512.0f);
            float var = Q * (1.0f / 512.0f) - muv * muv;
            mu[mt][r4] = muv;
            rs[mt][r4] = rsqrtf(var + 1e-5f);
        }

    // ---- pass 2: re-read gather, normalize, ReLU, store ----
    #pragma unroll
    for (int mt = 0; mt < 2; ++mt)
        #pragma unroll
        for (int nt = 0; nt < 4; ++nt) {
            int  c   = iv[nt];
            bool inb = (c < 512);
            int  cc  = inb ? c : 0;
            uint2 g = *(const uint2*)(y2 + cc * 38 + (mt << 4) + (q << 2));
            float gv[4];
            gv[0] = inb ? bflo(g.x) : 0.f;
            gv[1] = inb ? bfhi(g.x) : 0.f;
            gv[2] = inb ? bflo(g.y) : 0.f;
            gv[3] = inb ? bfhi(g.y) : 0.f;
            #pragma unroll
            for (int r4 = 0; r4 < 4; ++r4) {
                int r = (mt << 4) + (q << 2) + r4;
                float val = acc[mt][nt][r4] + gv[r4];
                float t   = (val - mu[mt][r4]) * rs[mt][r4];
                out[(((size_t)(b << 8) + o0 + r) << 9) + (wv << 6) + (nt << 4) + m] = fmaxf(t, 0.0f);
            }
        }
}

// ============================================================================
// Fallback (ws too small): round-2 fused single kernel, unchanged.
// ============================================================================
__global__ __launch_bounds__(256, 2)
void edgeconv_fused(const float* __restrict__ x,
                    const int*   __restrict__ idx,
                    const float* __restrict__ W,
                    float*       __restrict__ out)
{
    __shared__ __align__(16) unsigned char smem[65536];
    unsigned short* wlds = (unsigned short*)smem;
    unsigned short* xTl  = (unsigned short*)(smem + 32768);
    unsigned short* y2   = (unsigned short*)smem;
    float*          red  = (float*)(smem + 38912);

    const int tid  = threadIdx.x;
    const int wv   = tid >> 6;
    const int lane = tid & 63;
    const int m    = lane & 15;
    const int q    = lane >> 4;

    const int id  = blockIdx.x;
    const int rem = id & 63;
    const int b   = ((id >> 6) << 3) + (rem & 7);
    const int o0  = (rem >> 3) << 5;

    const float* xb = x + ((size_t)b << 17);

    #pragma unroll
    for (int i = 0; i < 16; ++i) {
        int r = (i << 2) + wv;
        const float4 f = *(const float4*)(W + ((size_t)(o0 + (r & 31)) << 9)
                                            + ((r >> 5) << 8) + (lane << 2));
        uint2 p; p.x = cvt2(f.x, f.y); p.y = cvt2(f.z, f.w);
        int sl = lane >> 1;
        *(uint2*)(wlds + (sl << 9) + ((swz(r) ^ (sl & 7)) << 3) + ((lane & 1) << 2)) = p;
    }

    f32x4 acc[4][8];
    #pragma unroll
    for (int mt = 0; mt < 4; ++mt)
        #pragma unroll
        for (int nt = 0; nt < 8; ++nt)
            acc[mt][nt] = (f32x4){0.f, 0.f, 0.f, 0.f};

    float4 xr0[8], xr1[8];
    auto loadg = [&](int kc, int g, float4* xr) {
        int gid = (g << 8) + tid;
        int s2  = gid >> 7;
        int l4  = gid & 127;
        const float* base = xb + ((size_t)((kc << 5) + (s2 << 3)) << 9) + (l4 << 2);
        #pragma unroll
        for (int j = 0; j < 8; ++j) xr[j] = *(const float4*)(base + (j << 9));
    };
    auto storeg = [&](int g, const float4* xr) {
        int gid = (g << 8) + tid;
        int s2  = gid >> 7;
        int l4  = gid & 127;
        #pragma unroll
        for (int lv = 0; lv < 4; ++lv) {
            int l = (l4 << 2) + lv;
            uint4 p;
            p.x = cvt2((&xr[0].x)[lv], (&xr[1].x)[lv]);
            p.y = cvt2((&xr[2].x)[lv], (&xr[3].x)[lv]);
            p.z = cvt2((&xr[4].x)[lv], (&xr[5].x)[lv]);
            p.w = cvt2((&xr[6].x)[lv], (&xr[7].x)[lv]);
            *(uint4*)(xTl + (s2 << 12) + (swz(l) << 3)) = p;
        }
    };

    loadg(0, 0, xr0);
    loadg(0, 1, xr1);
    storeg(0, xr0);
    storeg(1, xr1);
    __syncthreads();

    for (int kc = 0; kc < 8; ++kc) {
        if (kc < 7) loadg(kc + 1, 0, xr0);

        bf16x8 av[4], bv[8];
        #pragma unroll
        for (int mt = 0; mt < 4; ++mt) {
            int sl = (kc << 2) + q;
            av[mt] = *(const bf16x8*)(wlds + (sl << 9) + ((swz((mt << 4) + m) ^ (sl & 7)) << 3));
        }
        #pragma unroll
        for (int nt = 0; nt < 8; ++nt)
            bv[nt] = *(const bf16x8*)(xTl + (q << 12) + (swz((wv << 7) + (nt << 4) + m) << 3));

        #pragma unroll
        for (int mt = 0; mt < 4; ++mt)
            #pragma unroll
            for (int nt = 0; nt < 8; ++nt)
                acc[mt][nt] = __builtin_amdgcn_mfma_f32_16x16x32_bf16(av[mt], bv[nt], acc[mt][nt], 0, 0, 0);

        if (kc < 7) loadg(kc + 1, 1, xr1);
        __syncthreads();
        if (kc < 7) {
            storeg(0, xr0);
            storeg(1, xr1);
            __syncthreads();
        }
    }

    int iv[8];
    #pragma unroll
    for (int nt = 0; nt < 8; ++nt)
        iv[nt] = idx[((size_t)b << 9) + (wv << 7) + (nt << 4) + m];

    #pragma unroll
    for (int mt = 2; mt < 4; ++mt)
        #pragma unroll
        for (int nt = 0; nt < 8; ++nt) {
            int col  = (wv << 7) + (nt << 4) + m;
            int row0 = ((mt - 2) << 4) + (q << 2);
            uint2 p;
            p.x = cvt2(acc[mt][nt][0], acc[mt][nt][1]);
            p.y = cvt2(acc[mt][nt][2], acc[mt][nt][3]);
            *(uint2*)(y2 + col * 36 + row0) = p;
        }
    __syncthreads();

    float vvl[2][8][4];
    float s_[2][4], q_[2][4];
    #pragma unroll
    for (int mt = 0; mt < 2; ++mt)
        #pragma unroll
        for (int r4 = 0; r4 < 4; ++r4) { s_[mt][r4] = 0.f; q_[mt][r4] = 0.f; }

    #pragma unroll
    for (int nt = 0; nt < 8; ++nt) {
        int  c   = iv[nt];
        bool inb = (c < 512);
        int  cc  = inb ? c : 0;
        #pragma unroll
        for (int mt = 0; mt < 2; ++mt) {
            uint2 g = *(const uint2*)(y2 + cc * 36 + (mt << 4) + (q << 2));
            float gv[4];
            gv[0] = inb ? bflo(g.x) : 0.f;
            gv[1] = inb ? bfhi(g.x) : 0.f;
            gv[2] = inb ? bflo(g.y) : 0.f;
            gv[3] = inb ? bfhi(g.y) : 0.f;
            #pragma unroll
            for (int r4 = 0; r4 < 4; ++r4) {
                float val = acc[mt][nt][r4] + gv[r4];
                vvl[mt][nt][r4] = val;
                s_[mt][r4] += val;
                q_[mt][r4] += val * val;
            }
        }
    }

    #pragma unroll
    for (int mt = 0; mt < 2; ++mt)
        #pragma unroll
        for (int r4 = 0; r4 < 4; ++r4) {
            float s = s_[mt][r4], ss = q_[mt][r4];
            #pragma unroll
            for (int off = 1; off < 16; off <<= 1) {
                s  += __shfl_xor(s,  off, 64);
                ss += __shfl_xor(ss, off, 64);
            }
            if (m == 0) {
                int r = (mt << 4) + (q << 2) + r4;
                red[(r << 3) + (wv << 1)]     = s;
                red[(r << 3) + (wv << 1) + 1] = ss;
            }
        }
    __syncthreads();

    #pragma unroll
    for (int mt = 0; mt < 2; ++mt)
        #pragma unroll
        for (int r4 = 0; r4 < 4; ++r4) {
            int r = (mt << 4) + (q << 2) + r4;
            float S = red[(r << 3)]     + red[(r << 3) + 2] + red[(r << 3) + 4] + red[(r << 3) + 6];
            float Q = red[(r << 3) + 1] + red[(r << 3) + 3] + red[(r << 3) + 5] + red[(r << 3) + 7];
            float mu  = S * (1.0f / 512.0f);
            float var = Q * (1.0f / 512.0f) - mu * mu;
            float rs  = rsqrtf(var + 1e-5f);
            float* op = out + (((size_t)(b << 8) + o0 + r) << 9) + (wv << 7) + m;
            #pragma unroll
            for (int nt = 0; nt < 8; ++nt) {
                float t = (vvl[mt][nt][r4] - mu) * rs;
                op[nt << 4] = fmaxf(t, 0.0f);
            }
        }
}

extern "C" void kernel_launch(void* const* d_in, const int* in_sizes, int n_in,
                              void* d_out, int out_size, void* d_ws, size_t ws_size,
                              hipStream_t stream) {
    const float* x   = (const float*)d_in[0];   // [256,256,512] fp32
    const int*   idx = (const int*)  d_in[1];   // [256,512] int32, 512 == pad
    const float* W   = (const float*)d_in[2];   // [256,512] fp32
    // d_in[3] (bias) unused: constant-over-L shift cancels in InstanceNorm.
    float* out = (float*)d_out;                 // [256,256,512] fp32

    const size_t xT_bytes = (size_t)256 * 32 * 512 * 8 * 2;   // 67,108,864
    const size_t wT_bytes = (size_t)8 * 32 * 64 * 8 * 2;      // 262,144

    if (ws_size >= xT_bytes + wT_bytes) {
        unsigned short* xT = (unsigned short*)d_ws;
        unsigned short* wT = (unsigned short*)((char*)d_ws + xT_bytes);
        pack_transpose<<<dim3(2056), dim3(256), 0, stream>>>(x, W, xT, wT);
        edge_gemm<<<dim3(2048), dim3(512), 0, stream>>>(xT, wT, idx, out);
    } else {
        edgeconv_fused<<<dim3(2048), dim3(256), 0, stream>>>(x, idx, W, out);
    }
}

// Round 5
// 296.095 us; speedup vs baseline: 1.6795x; 1.1066x over previous
//
#include <hip/hip_runtime.h>
#include <hip/hip_bf16.h>
#include <stdint.h>

typedef __bf16 bf16x8 __attribute__((ext_vector_type(8)));
typedef float  f32x4  __attribute__((ext_vector_type(4)));

// packed fp32x2 -> bf16x2 (RNE) -- lowers to v_cvt_pk_bf16_f32 on gfx950
__device__ __forceinline__ uint32_t cvt2(float a, float b) {
    __hip_bfloat162 h = __float22bfloat162_rn(make_float2(a, b));
    uint32_t u; __builtin_memcpy(&u, &h, 4); return u;
}
__device__ __forceinline__ float bflo(uint32_t u) { uint32_t t = u << 16;         float f; __builtin_memcpy(&f, &t, 4); return f; }
__device__ __forceinline__ float bfhi(uint32_t u) { uint32_t t = u & 0xffff0000u; float f; __builtin_memcpy(&f, &t, 4); return f; }
__device__ __forceinline__ int swz(int u) { return u ^ ((u >> 3) & 7); }

// async global -> LDS DMA, 16 B/lane. LDS dest must be wave-uniform base + lane*16.
__device__ __forceinline__ void gload_lds16(const void* g, void* l) {
    __builtin_amdgcn_global_load_lds(
        (const __attribute__((address_space(1))) uint32_t*)g,
        (__attribute__((address_space(3))) uint32_t*)l,
        16, 0, 0);
}

// ============================================================================
// Kernel 1: pack x (and W) to bf16 in MFMA-fragment-ready transposed layouts.
//   xT[b][s][l][j] : k = s*8+j (s=0..31), l=0..511  -> B-frag = b128 at (b,s,col)
//   wT[og][s][r][j]: r<32 -> W1 row og*32+r, r>=32 -> W2 row og*32+r-32
// b == id (mod 8): written on the XCD that edge_gemm reads it from.
// ROUND-5 FIX: old store pattern was 16B @ 64B lane-stride (25% density, ~4x
// write amplification -> pack was 62us vs 30us traffic floor). Now the packs
// bounce through a 16KB LDS buffer (XOR-swizzled slots, involution a^((a>>3)&7))
// and are stored back as contiguous 4KB runs (lane t -> slot i*256+t).
// ============================================================================
__global__ __launch_bounds__(256, 4)
void pack_transpose(const float* __restrict__ x, const float* __restrict__ W,
                    unsigned short* __restrict__ xT, unsigned short* __restrict__ wT)
{
    const int tid = threadIdx.x;
    const int id  = blockIdx.x;
    if (id < 2048) {
        __shared__ __align__(16) uint4 lbuf[1024];       // 16 KB, reused per half
        const int b  = ((id >> 6) << 3) + (id & 7);      // XCD-matched: b % 8 == id % 8
        const int kc = (id >> 3) & 7;
        const int s2 = tid >> 6, l4 = tid & 63;          // slab-in-chunk, l-quad
        const float* src0 = x + ((size_t)b << 17) + ((size_t)((kc << 5) + (s2 << 3)) << 9);
        unsigned short* dstb = xT + (((size_t)(b << 5) + (kc << 2)) << 12);  // 4-slab base
        #pragma unroll
        for (int lh = 0; lh < 2; ++lh) {
            const int l0 = (lh << 8) + (l4 << 2);
            f32x4 xr[8];
            #pragma unroll
            for (int j = 0; j < 8; ++j)
                xr[j] = __builtin_nontemporal_load((const f32x4*)(src0 + (j << 9) + l0));
            if (lh) __syncthreads();     // half-0 readers done before half-1 writes
            #pragma unroll
            for (int lv = 0; lv < 4; ++lv) {
                uint4 p;
                p.x = cvt2(xr[0][lv], xr[1][lv]);
                p.y = cvt2(xr[2][lv], xr[3][lv]);
                p.z = cvt2(xr[4][lv], xr[5][lv]);
                p.w = cvt2(xr[6][lv], xr[7][lv]);
                int a = (s2 << 8) + (l4 << 2) + lv;      // slot = s2*256 + l-in-half
                lbuf[a ^ ((a >> 3) & 7)] = p;            // swizzled ds_write_b128
            }
            __syncthreads();
            #pragma unroll
            for (int i = 0; i < 4; ++i) {                // lane t -> slot i*256+t:
                int a = (i << 8) + tid;                  // global stores 4KB-contiguous
                uint4 v = lbuf[a ^ ((a >> 3) & 7)];
                *(uint4*)(dstb + ((size_t)i << 12) + (((lh << 8) + tid) << 3)) = v;
            }
        }
    } else {
        const int og = id - 2048;
        const int r = tid & 63, sg = tid >> 6;
        const float* wrow = W + ((size_t)((og << 5) + (r & 31)) << 9) + ((r >> 5) << 8);
        #pragma unroll
        for (int ss = 0; ss < 8; ++ss) {
            const int s = (sg << 3) + ss;
            float4 f0 = *(const float4*)(wrow + (s << 3));
            float4 f1 = *(const float4*)(wrow + (s << 3) + 4);
            uint4 p;
            p.x = cvt2(f0.x, f0.y); p.y = cvt2(f0.z, f0.w);
            p.z = cvt2(f1.x, f1.y); p.w = cvt2(f1.z, f1.w);
            *(uint4*)(wT + (((((og << 5) + s) << 6) + r) << 3)) = p;
        }
    }
}

// ============================================================================
// Kernel 2: GEMM -- round-1 known-good structure (best measured: ~68us).
// 256 thr / 4 waves, block = (b, og), acc[4][8], 2-phase async-DMA LDS
// double-buffer, one __syncthreads per chunk. Rounds 2-4 lessons baked in:
// no asm waitcnt pins (regressed), no 512-thr/wave-split (spilled), plain
// stores (NT added +19MB write), y2 gather stride 34 (17 coprime 32 ->
// conflict-free, and 34*512*2+1KB red fits inside buf0 so kc=7 (buf1) is
// never overlaid).
// ============================================================================
__global__ __launch_bounds__(256, 2)
void edge_gemm(const unsigned short* __restrict__ xT,
               const unsigned short* __restrict__ wT,
               const int* __restrict__ idx,
               float* __restrict__ out)
{
    // buf k at smem + k*36864: B [32768 B] then A [4096 B]
    // epilogue overlay (inside buf0): y2 bf16 [512 col][34] = 34816 B @0,
    //                                 red fp32 [32 r][4 wv][2] = 1 KB @34816
    __shared__ __align__(16) unsigned char smem[73728];
    unsigned short* y2 = (unsigned short*)smem;
    float* red         = (float*)(smem + 34816);

    const int tid  = threadIdx.x;
    const int wv   = tid >> 6;
    const int lane = tid & 63;
    const int m    = lane & 15;
    const int q    = lane >> 4;

    // XCD swizzle: 8 o-blocks of one b are 8 ids apart -> same XCD round-robin
    const int id  = blockIdx.x;
    const int rem = id & 63;
    const int b   = ((id >> 6) << 3) + (rem & 7);
    const int og  = rem >> 3;
    const int o0  = og << 5;

    const char* xb = (const char*)xT + ((size_t)b << 18); // b * 256 KB
    const char* wb = (const char*)wT + (og << 15);        // og * 32 KB

    const int offS = tid << 4;                            // per-wave-linear 16B slots

    int iv[8];
    #pragma unroll
    for (int nt = 0; nt < 8; ++nt)
        iv[nt] = idx[((size_t)b << 9) + (wv << 7) + (nt << 4) + m];

    f32x4 acc[4][8];
    #pragma unroll
    for (int mt = 0; mt < 4; ++mt)
        #pragma unroll
        for (int nt = 0; nt < 8; ++nt)
            acc[mt][nt] = (f32x4){0.f, 0.f, 0.f, 0.f};

    auto stage = [&](int c, int bsel) {
        char* Bl = (char*)smem + bsel * 36864;
        const char* Bg = xb + ((size_t)c << 15);
        #pragma unroll
        for (int i = 0; i < 8; ++i)
            gload_lds16(Bg + (i << 12) + offS, Bl + (i << 12) + offS);
        gload_lds16(wb + (c << 12) + offS, Bl + 32768 + offS);
    };

    // ---- prologue: chunk 0 -> buf 0 ----
    stage(0, 0);
    __syncthreads();

    // ---- K loop: issue next-chunk DMA, compute current, one barrier ----
    #pragma unroll
    for (int kc = 0; kc < 8; ++kc) {
        const int cur = kc & 1;
        if (kc < 7) stage(kc + 1, cur ^ 1);

        const unsigned short* B0 = (const unsigned short*)(smem + cur * 36864);
        const unsigned short* A0 = B0 + 16384;            // +32768 bytes
        bf16x8 av[4], bv[8];
        #pragma unroll
        for (int mt = 0; mt < 4; ++mt)
            av[mt] = *(const bf16x8*)(A0 + (q << 9) + (((mt << 4) + m) << 3));
        #pragma unroll
        for (int nt = 0; nt < 8; ++nt)
            bv[nt] = *(const bf16x8*)(B0 + (q << 12) + (((wv << 7) + (nt << 4) + m) << 3));
        #pragma unroll
        for (int mt = 0; mt < 4; ++mt)
            #pragma unroll
            for (int nt = 0; nt < 8; ++nt)
                acc[mt][nt] = __builtin_amdgcn_mfma_f32_16x16x32_bf16(av[mt], bv[nt], acc[mt][nt], 0, 0, 0);

        if (kc < 7) __syncthreads();
    }

    // ---- epilogue: Y2 -> y2 (stride 34: 17 coprime 32, conflict-free).
    // kc=7 computed from buf1 (36864..); y2/red live in buf0 -- disjoint. ----
    #pragma unroll
    for (int mt = 2; mt < 4; ++mt)
        #pragma unroll
        for (int nt = 0; nt < 8; ++nt) {
            int col  = (wv << 7) + (nt << 4) + m;
            int row0 = ((mt - 2) << 4) + (q << 2);
            uint2 p;
            p.x = cvt2(acc[mt][nt][0], acc[mt][nt][1]);
            p.y = cvt2(acc[mt][nt][2], acc[mt][nt][3]);
            *(uint2*)(y2 + col * 34 + row0) = p;
        }
    __syncthreads();

    float vvl[2][8][4];
    float s_[2][4], q_[2][4];
    #pragma unroll
    for (int mt = 0; mt < 2; ++mt)
        #pragma unroll
        for (int r4 = 0; r4 < 4; ++r4) { s_[mt][r4] = 0.f; q_[mt][r4] = 0.f; }

    #pragma unroll
    for (int nt = 0; nt < 8; ++nt) {
        int  c   = iv[nt];
        bool inb = (c < 512);                    // idx==512 -> pad column (zero)
        int  cc  = inb ? c : 0;
        #pragma unroll
        for (int mt = 0; mt < 2; ++mt) {
            uint2 g = *(const uint2*)(y2 + cc * 34 + (mt << 4) + (q << 2));
            float gv[4];
            gv[0] = inb ? bflo(g.x) : 0.f;
            gv[1] = inb ? bfhi(g.x) : 0.f;
            gv[2] = inb ? bflo(g.y) : 0.f;
            gv[3] = inb ? bfhi(g.y) : 0.f;
            #pragma unroll
            for (int r4 = 0; r4 < 4; ++r4) {
                float val = acc[mt][nt][r4] + gv[r4];
                vvl[mt][nt][r4] = val;
                s_[mt][r4] += val;
                q_[mt][r4] += val * val;
            }
        }
    }

    // reduce: 16-lane butterfly over m, cross-wave via red
    #pragma unroll
    for (int mt = 0; mt < 2; ++mt)
        #pragma unroll
        for (int r4 = 0; r4 < 4; ++r4) {
            float s = s_[mt][r4], ss = q_[mt][r4];
            #pragma unroll
            for (int off = 1; off < 16; off <<= 1) {
                s  += __shfl_xor(s,  off, 64);
                ss += __shfl_xor(ss, off, 64);
            }
            if (m == 0) {
                int r = (mt << 4) + (q << 2) + r4;
                red[(r << 3) + (wv << 1)]     = s;
                red[(r << 3) + (wv << 1) + 1] = ss;
            }
        }
    __syncthreads();

    #pragma unroll
    for (int mt = 0; mt < 2; ++mt)
        #pragma unroll
        for (int r4 = 0; r4 < 4; ++r4) {
            int r = (mt << 4) + (q << 2) + r4;
            float S = red[(r << 3)]     + red[(r << 3) + 2] + red[(r << 3) + 4] + red[(r << 3) + 6];
            float Q = red[(r << 3) + 1] + red[(r << 3) + 3] + red[(r << 3) + 5] + red[(r << 3) + 7];
            float mu  = S * (1.0f / 512.0f);
            float var = Q * (1.0f / 512.0f) - mu * mu;
            float rs  = rsqrtf(var + 1e-5f);
            float* op = out + (((size_t)(b << 8) + o0 + r) << 9) + (wv << 7) + m;
            #pragma unroll
            for (int nt = 0; nt < 8; ++nt) {
                float t = (vvl[mt][nt][r4] - mu) * rs;
                op[nt << 4] = fmaxf(t, 0.0f);
            }
        }
}

// ============================================================================
// Fallback (ws too small): round-2 fused single kernel, unchanged.
// ============================================================================
__global__ __launch_bounds__(256, 2)
void edgeconv_fused(const float* __restrict__ x,
                    const int*   __restrict__ idx,
                    const float* __restrict__ W,
                    float*       __restrict__ out)
{
    __shared__ __align__(16) unsigned char smem[65536];
    unsigned short* wlds = (unsigned short*)smem;
    unsigned short* xTl  = (unsigned short*)(smem + 32768);
    unsigned short* y2   = (unsigned short*)smem;
    float*          red  = (float*)(smem + 38912);

    const int tid  = threadIdx.x;
    const int wv   = tid >> 6;
    const int lane = tid & 63;
    const int m    = lane & 15;
    const int q    = lane >> 4;

    const int id  = blockIdx.x;
    const int rem = id & 63;
    const int b   = ((id >> 6) << 3) + (rem & 7);
    const int o0  = (rem >> 3) << 5;

    const float* xb = x + ((size_t)b << 17);

    #pragma unroll
    for (int i = 0; i < 16; ++i) {
        int r = (i << 2) + wv;
        const float4 f = *(const float4*)(W + ((size_t)(o0 + (r & 31)) << 9)
                                            + ((r >> 5) << 8) + (lane << 2));
        uint2 p; p.x = cvt2(f.x, f.y); p.y = cvt2(f.z, f.w);
        int sl = lane >> 1;
        *(uint2*)(wlds + (sl << 9) + ((swz(r) ^ (sl & 7)) << 3) + ((lane & 1) << 2)) = p;
    }

    f32x4 acc[4][8];
    #pragma unroll
    for (int mt = 0; mt < 4; ++mt)
        #pragma unroll
        for (int nt = 0; nt < 8; ++nt)
            acc[mt][nt] = (f32x4){0.f, 0.f, 0.f, 0.f};

    float4 xr0[8], xr1[8];
    auto loadg = [&](int kc, int g, float4* xr) {
        int gid = (g << 8) + tid;
        int s2  = gid >> 7;
        int l4  = gid & 127;
        const float* base = xb + ((size_t)((kc << 5) + (s2 << 3)) << 9) + (l4 << 2);
        #pragma unroll
        for (int j = 0; j < 8; ++j) xr[j] = *(const float4*)(base + (j << 9));
    };
    auto storeg = [&](int g, const float4* xr) {
        int gid = (g << 8) + tid;
        int s2  = gid >> 7;
        int l4  = gid & 127;
        #pragma unroll
        for (int lv = 0; lv < 4; ++lv) {
            int l = (l4 << 2) + lv;
            uint4 p;
            p.x = cvt2((&xr[0].x)[lv], (&xr[1].x)[lv]);
            p.y = cvt2((&xr[2].x)[lv], (&xr[3].x)[lv]);
            p.z = cvt2((&xr[4].x)[lv], (&xr[5].x)[lv]);
            p.w = cvt2((&xr[6].x)[lv], (&xr[7].x)[lv]);
            *(uint4*)(xTl + (s2 << 12) + (swz(l) << 3)) = p;
        }
    };

    loadg(0, 0, xr0);
    loadg(0, 1, xr1);
    storeg(0, xr0);
    storeg(1, xr1);
    __syncthreads();

    for (int kc = 0; kc < 8; ++kc) {
        if (kc < 7) loadg(kc + 1, 0, xr0);

        bf16x8 av[4], bv[8];
        #pragma unroll
        for (int mt = 0; mt < 4; ++mt) {
            int sl = (kc << 2) + q;
            av[mt] = *(const bf16x8*)(wlds + (sl << 9) + ((swz((mt << 4) + m) ^ (sl & 7)) << 3));
        }
        #pragma unroll
        for (int nt = 0; nt < 8; ++nt)
            bv[nt] = *(const bf16x8*)(xTl + (q << 12) + (swz((wv << 7) + (nt << 4) + m) << 3));

        #pragma unroll
        for (int mt = 0; mt < 4; ++mt)
            #pragma unroll
            for (int nt = 0; nt < 8; ++nt)
                acc[mt][nt] = __builtin_amdgcn_mfma_f32_16x16x32_bf16(av[mt], bv[nt], acc[mt][nt], 0, 0, 0);

        if (kc < 7) loadg(kc + 1, 1, xr1);
        __syncthreads();
        if (kc < 7) {
            storeg(0, xr0);
            storeg(1, xr1);
            __syncthreads();
        }
    }

    int iv[8];
    #pragma unroll
    for (int nt = 0; nt < 8; ++nt)
        iv[nt] = idx[((size_t)b << 9) + (wv << 7) + (nt << 4) + m];

    #pragma unroll
    for (int mt = 2; mt < 4; ++mt)
        #pragma unroll
        for (int nt = 0; nt < 8; ++nt) {
            int col  = (wv << 7) + (nt << 4) + m;
            int row0 = ((mt - 2) << 4) + (q << 2);
            uint2 p;
            p.x = cvt2(acc[mt][nt][0], acc[mt][nt][1]);
            p.y = cvt2(acc[mt][nt][2], acc[mt][nt][3]);
            *(uint2*)(y2 + col * 36 + row0) = p;
        }
    __syncthreads();

    float vvl[2][8][4];
    float s_[2][4], q_[2][4];
    #pragma unroll
    for (int mt = 0; mt < 2; ++mt)
        #pragma unroll
        for (int r4 = 0; r4 < 4; ++r4) { s_[mt][r4] = 0.f; q_[mt][r4] = 0.f; }

    #pragma unroll
    for (int nt = 0; nt < 8; ++nt) {
        int  c   = iv[nt];
        bool inb = (c < 512);
        int  cc  = inb ? c : 0;
        #pragma unroll
        for (int mt = 0; mt < 2; ++mt) {
            uint2 g = *(const uint2*)(y2 + cc * 36 + (mt << 4) + (q << 2));
            float gv[4];
            gv[0] = inb ? bflo(g.x) : 0.f;
            gv[1] = inb ? bfhi(g.x) : 0.f;
            gv[2] = inb ? bflo(g.y) : 0.f;
            gv[3] = inb ? bfhi(g.y) : 0.f;
            #pragma unroll
            for (int r4 = 0; r4 < 4; ++r4) {
                float val = acc[mt][nt][r4] + gv[r4];
                vvl[mt][nt][r4] = val;
                s_[mt][r4] += val;
                q_[mt][r4] += val * val;
            }
        }
    }

    #pragma unroll
    for (int mt = 0; mt < 2; ++mt)
        #pragma unroll
        for (int r4 = 0; r4 < 4; ++r4) {
            float s = s_[mt][r4], ss = q_[mt][r4];
            #pragma unroll
            for (int off = 1; off < 16; off <<= 1) {
                s  += __shfl_xor(s,  off, 64);
                ss += __shfl_xor(ss, off, 64);
            }
            if (m == 0) {
                int r = (mt << 4) + (q << 2) + r4;
                red[(r << 3) + (wv << 1)]     = s;
                red[(r << 3) + (wv << 1) + 1] = ss;
            }
        }
    __syncthreads();

    #pragma unroll
    for (int mt = 0; mt < 2; ++mt)
        #pragma unroll
        for (int r4 = 0; r4 < 4; ++r4) {
            int r = (mt << 4) + (q << 2) + r4;
            float S = red[(r << 3)]     + red[(r << 3) + 2] + red[(r << 3) + 4] + red[(r << 3) + 6];
            float Q = red[(r << 3) + 1] + red[(r << 3) + 3] + red[(r << 3) + 5] + red[(r << 3) + 7];
            float mu  = S * (1.0f / 512.0f);
            float var = Q * (1.0f / 512.0f) - mu * mu;
            float rs  = rsqrtf(var + 1e-5f);
            float* op = out + (((size_t)(b << 8) + o0 + r) << 9) + (wv << 7) + m;
            #pragma unroll
            for (int nt = 0; nt < 8; ++nt) {
                float t = (vvl[mt][nt][r4] - mu) * rs;
                op[nt << 4] = fmaxf(t, 0.0f);
            }
        }
}

extern "C" void kernel_launch(void* const* d_in, const int* in_sizes, int n_in,
                              void* d_out, int out_size, void* d_ws, size_t ws_size,
                              hipStream_t stream) {
    const float* x   = (const float*)d_in[0];   // [256,256,512] fp32
    const int*   idx = (const int*)  d_in[1];   // [256,512] int32, 512 == pad
    const float* W   = (const float*)d_in[2];   // [256,512] fp32
    // d_in[3] (bias) unused: constant-over-L shift cancels in InstanceNorm.
    float* out = (float*)d_out;                 // [256,256,512] fp32

    const size_t xT_bytes = (size_t)256 * 32 * 512 * 8 * 2;   // 67,108,864
    const size_t wT_bytes = (size_t)8 * 32 * 64 * 8 * 2;      // 262,144

    if (ws_size >= xT_bytes + wT_bytes) {
        unsigned short* xT = (unsigned short*)d_ws;
        unsigned short* wT = (unsigned short*)((char*)d_ws + xT_bytes);
        pack_transpose<<<dim3(2056), dim3(256), 0, stream>>>(x, W, xT, wT);
        edge_gemm<<<dim3(2048), dim3(256), 0, stream>>>(xT, wT, idx, out);
    } else {
        edgeconv_fused<<<dim3(2048), dim3(256), 0, stream>>>(x, idx, W, out);
    }
}

// Round 6
// 294.031 us; speedup vs baseline: 1.6913x; 1.0070x over previous
//
#include <hip/hip_runtime.h>
#include <hip/hip_bf16.h>
#include <stdint.h>

typedef __bf16 bf16x8 __attribute__((ext_vector_type(8)));
typedef float  f32x4  __attribute__((ext_vector_type(4)));

// packed fp32x2 -> bf16x2 (RNE) -- lowers to v_cvt_pk_bf16_f32 on gfx950
__device__ __forceinline__ uint32_t cvt2(float a, float b) {
    __hip_bfloat162 h = __float22bfloat162_rn(make_float2(a, b));
    uint32_t u; __builtin_memcpy(&u, &h, 4); return u;
}
__device__ __forceinline__ float bflo(uint32_t u) { uint32_t t = u << 16;         float f; __builtin_memcpy(&f, &t, 4); return f; }
__device__ __forceinline__ float bfhi(uint32_t u) { uint32_t t = u & 0xffff0000u; float f; __builtin_memcpy(&f, &t, 4); return f; }
__device__ __forceinline__ int swz(int u) { return u ^ ((u >> 3) & 7); }

// async global -> LDS DMA, 16 B/lane. LDS dest must be wave-uniform base + lane*16.
__device__ __forceinline__ void gload_lds16(const void* g, void* l) {
    __builtin_amdgcn_global_load_lds(
        (const __attribute__((address_space(1))) uint32_t*)g,
        (__attribute__((address_space(3))) uint32_t*)l,
        16, 0, 0);
}

// ============================================================================
// Kernel 1: pack x (and W) to bf16 in MFMA-fragment-ready transposed layouts.
//   xT[b][s][l][j] : k = s*8+j (s=0..31), l=0..511  -> B-frag = b128 at (b,s,col)
//   wT[og][s][r][j]: r<32 -> W1 row og*32+r, r>=32 -> W2 row og*32+r-32
// ROUND-6: grid doubled to 4096 x-blocks (one lh half each, b%8 == id%8 kept)
// -- pack was latency-bound on NT loads at 2048 blocks (48.7us vs 30us floor).
// LDS-bounce store path (round-5 win) unchanged: swizzled 16KB buffer, then
// contiguous 4KB-run global stores.
// ============================================================================
__global__ __launch_bounds__(256, 4)
void pack_transpose(const float* __restrict__ x, const float* __restrict__ W,
                    unsigned short* __restrict__ xT, unsigned short* __restrict__ wT)
{
    const int tid = threadIdx.x;
    const int id  = blockIdx.x;
    if (id < 4096) {
        __shared__ __align__(16) uint4 lbuf[1024];       // 16 KB
        const int b  = ((id >> 7) << 3) + (id & 7);      // XCD-matched: b % 8 == id % 8
        const int lh = (id >> 3) & 1;                    // which 256-col half
        const int kc = (id >> 4) & 7;
        const int s2 = tid >> 6, l4 = tid & 63;          // slab-in-chunk, l-quad
        const float* src0 = x + ((size_t)b << 17) + ((size_t)((kc << 5) + (s2 << 3)) << 9);
        unsigned short* dstb = xT + (((size_t)(b << 5) + (kc << 2)) << 12);  // 4-slab base
        const int l0 = (lh << 8) + (l4 << 2);
        f32x4 xr[8];
        #pragma unroll
        for (int j = 0; j < 8; ++j)
            xr[j] = __builtin_nontemporal_load((const f32x4*)(src0 + (j << 9) + l0));
        #pragma unroll
        for (int lv = 0; lv < 4; ++lv) {
            uint4 p;
            p.x = cvt2(xr[0][lv], xr[1][lv]);
            p.y = cvt2(xr[2][lv], xr[3][lv]);
            p.z = cvt2(xr[4][lv], xr[5][lv]);
            p.w = cvt2(xr[6][lv], xr[7][lv]);
            int a = (s2 << 8) + (l4 << 2) + lv;          // slot = s2*256 + l-in-half
            lbuf[a ^ ((a >> 3) & 7)] = p;                // swizzled ds_write_b128
        }
        __syncthreads();
        #pragma unroll
        for (int i = 0; i < 4; ++i) {                    // lane t -> slot i*256+t:
            int a = (i << 8) + tid;                      // global stores 4KB-contiguous
            uint4 v = lbuf[a ^ ((a >> 3) & 7)];
            *(uint4*)(dstb + ((size_t)i << 12) + (((lh << 8) + tid) << 3)) = v;
        }
    } else {
        const int og = id - 4096;
        const int r = tid & 63, sg = tid >> 6;
        const float* wrow = W + ((size_t)((og << 5) + (r & 31)) << 9) + ((r >> 5) << 8);
        #pragma unroll
        for (int ss = 0; ss < 8; ++ss) {
            const int s = (sg << 3) + ss;
            float4 f0 = *(const float4*)(wrow + (s << 3));
            float4 f1 = *(const float4*)(wrow + (s << 3) + 4);
            uint4 p;
            p.x = cvt2(f0.x, f0.y); p.y = cvt2(f0.z, f0.w);
            p.z = cvt2(f1.x, f1.y); p.w = cvt2(f1.z, f1.w);
            *(uint4*)(wT + (((((og << 5) + s) << 6) + r) << 3)) = p;
        }
    }
}

// ============================================================================
// Kernel 2: GEMM -- round-5 structure (2-phase DMA dbuf, stride-34 conflict-
// free epilogue: SQ_LDS_BANK_CONFLICT=256) + ROUND-6: nontemporal out stores
// restored. Evidence: R1 (NT) gemm <=78.4us vs R5 (plain, same structure)
// 89.4us. Mechanism: the 134MB out stream evicts xT (67MB) from LLC -> 55% of
// xT re-fetched from HBM at ~900cyc into every barrier drain. NT stores
// bypass the cache hierarchy, keeping xT LLC-resident (~+20MB WRITE, -12MB
// FETCH, and the DMA drain drops to LLC latency). Occupancy is reg-locked at
// 2 waves/SIMD (acc[4][8]=128 + ~124 VGPR vs 512/SIMD pool) -- latency
// reduction is the only remaining lever.
// ============================================================================
__global__ __launch_bounds__(256, 2)
void edge_gemm(const unsigned short* __restrict__ xT,
               const unsigned short* __restrict__ wT,
               const int* __restrict__ idx,
               float* __restrict__ out)
{
    // buf k at smem + k*36864: B [32768 B] then A [4096 B]
    // epilogue overlay (inside buf0): y2 bf16 [512 col][34] = 34816 B @0,
    //                                 red fp32 [32 r][4 wv][2] = 1 KB @34816
    __shared__ __align__(16) unsigned char smem[73728];
    unsigned short* y2 = (unsigned short*)smem;
    float* red         = (float*)(smem + 34816);

    const int tid  = threadIdx.x;
    const int wv   = tid >> 6;
    const int lane = tid & 63;
    const int m    = lane & 15;
    const int q    = lane >> 4;

    // XCD swizzle: 8 o-blocks of one b are 8 ids apart -> same XCD round-robin
    const int id  = blockIdx.x;
    const int rem = id & 63;
    const int b   = ((id >> 6) << 3) + (rem & 7);
    const int og  = rem >> 3;
    const int o0  = og << 5;

    const char* xb = (const char*)xT + ((size_t)b << 18); // b * 256 KB
    const char* wb = (const char*)wT + (og << 15);        // og * 32 KB

    const int offS = tid << 4;                            // per-wave-linear 16B slots

    int iv[8];
    #pragma unroll
    for (int nt = 0; nt < 8; ++nt)
        iv[nt] = idx[((size_t)b << 9) + (wv << 7) + (nt << 4) + m];

    f32x4 acc[4][8];
    #pragma unroll
    for (int mt = 0; mt < 4; ++mt)
        #pragma unroll
        for (int nt = 0; nt < 8; ++nt)
            acc[mt][nt] = (f32x4){0.f, 0.f, 0.f, 0.f};

    auto stage = [&](int c, int bsel) {
        char* Bl = (char*)smem + bsel * 36864;
        const char* Bg = xb + ((size_t)c << 15);
        #pragma unroll
        for (int i = 0; i < 8; ++i)
            gload_lds16(Bg + (i << 12) + offS, Bl + (i << 12) + offS);
        gload_lds16(wb + (c << 12) + offS, Bl + 32768 + offS);
    };

    // ---- prologue: chunk 0 -> buf 0 ----
    stage(0, 0);
    __syncthreads();

    // ---- K loop: issue next-chunk DMA, compute current, one barrier ----
    #pragma unroll
    for (int kc = 0; kc < 8; ++kc) {
        const int cur = kc & 1;
        if (kc < 7) stage(kc + 1, cur ^ 1);

        const unsigned short* B0 = (const unsigned short*)(smem + cur * 36864);
        const unsigned short* A0 = B0 + 16384;            // +32768 bytes
        bf16x8 av[4], bv[8];
        #pragma unroll
        for (int mt = 0; mt < 4; ++mt)
            av[mt] = *(const bf16x8*)(A0 + (q << 9) + (((mt << 4) + m) << 3));
        #pragma unroll
        for (int nt = 0; nt < 8; ++nt)
            bv[nt] = *(const bf16x8*)(B0 + (q << 12) + (((wv << 7) + (nt << 4) + m) << 3));
        #pragma unroll
        for (int mt = 0; mt < 4; ++mt)
            #pragma unroll
            for (int nt = 0; nt < 8; ++nt)
                acc[mt][nt] = __builtin_amdgcn_mfma_f32_16x16x32_bf16(av[mt], bv[nt], acc[mt][nt], 0, 0, 0);

        if (kc < 7) __syncthreads();
    }

    // ---- epilogue: Y2 -> y2 (stride 34: 17 coprime 32, conflict-free).
    // kc=7 computed from buf1 (36864..); y2/red live in buf0 -- disjoint. ----
    #pragma unroll
    for (int mt = 2; mt < 4; ++mt)
        #pragma unroll
        for (int nt = 0; nt < 8; ++nt) {
            int col  = (wv << 7) + (nt << 4) + m;
            int row0 = ((mt - 2) << 4) + (q << 2);
            uint2 p;
            p.x = cvt2(acc[mt][nt][0], acc[mt][nt][1]);
            p.y = cvt2(acc[mt][nt][2], acc[mt][nt][3]);
            *(uint2*)(y2 + col * 34 + row0) = p;
        }
    __syncthreads();

    float vvl[2][8][4];
    float s_[2][4], q_[2][4];
    #pragma unroll
    for (int mt = 0; mt < 2; ++mt)
        #pragma unroll
        for (int r4 = 0; r4 < 4; ++r4) { s_[mt][r4] = 0.f; q_[mt][r4] = 0.f; }

    #pragma unroll
    for (int nt = 0; nt < 8; ++nt) {
        int  c   = iv[nt];
        bool inb = (c < 512);                    // idx==512 -> pad column (zero)
        int  cc  = inb ? c : 0;
        #pragma unroll
        for (int mt = 0; mt < 2; ++mt) {
            uint2 g = *(const uint2*)(y2 + cc * 34 + (mt << 4) + (q << 2));
            float gv[4];
            gv[0] = inb ? bflo(g.x) : 0.f;
            gv[1] = inb ? bfhi(g.x) : 0.f;
            gv[2] = inb ? bflo(g.y) : 0.f;
            gv[3] = inb ? bfhi(g.y) : 0.f;
            #pragma unroll
            for (int r4 = 0; r4 < 4; ++r4) {
                float val = acc[mt][nt][r4] + gv[r4];
                vvl[mt][nt][r4] = val;
                s_[mt][r4] += val;
                q_[mt][r4] += val * val;
            }
        }
    }

    // reduce: 16-lane butterfly over m, cross-wave via red
    #pragma unroll
    for (int mt = 0; mt < 2; ++mt)
        #pragma unroll
        for (int r4 = 0; r4 < 4; ++r4) {
            float s = s_[mt][r4], ss = q_[mt][r4];
            #pragma unroll
            for (int off = 1; off < 16; off <<= 1) {
                s  += __shfl_xor(s,  off, 64);
                ss += __shfl_xor(ss, off, 64);
            }
            if (m == 0) {
                int r = (mt << 4) + (q << 2) + r4;
                red[(r << 3) + (wv << 1)]     = s;
                red[(r << 3) + (wv << 1) + 1] = ss;
            }
        }
    __syncthreads();

    #pragma unroll
    for (int mt = 0; mt < 2; ++mt)
        #pragma unroll
        for (int r4 = 0; r4 < 4; ++r4) {
            int r = (mt << 4) + (q << 2) + r4;
            float S = red[(r << 3)]     + red[(r << 3) + 2] + red[(r << 3) + 4] + red[(r << 3) + 6];
            float Q = red[(r << 3) + 1] + red[(r << 3) + 3] + red[(r << 3) + 5] + red[(r << 3) + 7];
            float mu  = S * (1.0f / 512.0f);
            float var = Q * (1.0f / 512.0f) - mu * mu;
            float rs  = rsqrtf(var + 1e-5f);
            float* op = out + (((size_t)(b << 8) + o0 + r) << 9) + (wv << 7) + m;
            #pragma unroll
            for (int nt = 0; nt < 8; ++nt) {
                float t = (vvl[mt][nt][r4] - mu) * rs;
                __builtin_nontemporal_store(fmaxf(t, 0.0f), op + (nt << 4));
            }
        }
}

// ============================================================================
// Fallback (ws too small): round-2 fused single kernel, unchanged.
// ============================================================================
__global__ __launch_bounds__(256, 2)
void edgeconv_fused(const float* __restrict__ x,
                    const int*   __restrict__ idx,
                    const float* __restrict__ W,
                    float*       __restrict__ out)
{
    __shared__ __align__(16) unsigned char smem[65536];
    unsigned short* wlds = (unsigned short*)smem;
    unsigned short* xTl  = (unsigned short*)(smem + 32768);
    unsigned short* y2   = (unsigned short*)smem;
    float*          red  = (float*)(smem + 38912);

    const int tid  = threadIdx.x;
    const int wv   = tid >> 6;
    const int lane = tid & 63;
    const int m    = lane & 15;
    const int q    = lane >> 4;

    const int id  = blockIdx.x;
    const int rem = id & 63;
    const int b   = ((id >> 6) << 3) + (rem & 7);
    const int o0  = (rem >> 3) << 5;

    const float* xb = x + ((size_t)b << 17);

    #pragma unroll
    for (int i = 0; i < 16; ++i) {
        int r = (i << 2) + wv;
        const float4 f = *(const float4*)(W + ((size_t)(o0 + (r & 31)) << 9)
                                            + ((r >> 5) << 8) + (lane << 2));
        uint2 p; p.x = cvt2(f.x, f.y); p.y = cvt2(f.z, f.w);
        int sl = lane >> 1;
        *(uint2*)(wlds + (sl << 9) + ((swz(r) ^ (sl & 7)) << 3) + ((lane & 1) << 2)) = p;
    }

    f32x4 acc[4][8];
    #pragma unroll
    for (int mt = 0; mt < 4; ++mt)
        #pragma unroll
        for (int nt = 0; nt < 8; ++nt)
            acc[mt][nt] = (f32x4){0.f, 0.f, 0.f, 0.f};

    float4 xr0[8], xr1[8];
    auto loadg = [&](int kc, int g, float4* xr) {
        int gid = (g << 8) + tid;
        int s2  = gid >> 7;
        int l4  = gid & 127;
        const float* base = xb + ((size_t)((kc << 5) + (s2 << 3)) << 9) + (l4 << 2);
        #pragma unroll
        for (int j = 0; j < 8; ++j) xr[j] = *(const float4*)(base + (j << 9));
    };
    auto storeg = [&](int g, const float4* xr) {
        int gid = (g << 8) + tid;
        int s2  = gid >> 7;
        int l4  = gid & 127;
        #pragma unroll
        for (int lv = 0; lv < 4; ++lv) {
            int l = (l4 << 2) + lv;
            uint4 p;
            p.x = cvt2((&xr[0].x)[lv], (&xr[1].x)[lv]);
            p.y = cvt2((&xr[2].x)[lv], (&xr[3].x)[lv]);
            p.z = cvt2((&xr[4].x)[lv], (&xr[5].x)[lv]);
            p.w = cvt2((&xr[6].x)[lv], (&xr[7].x)[lv]);
            *(uint4*)(xTl + (s2 << 12) + (swz(l) << 3)) = p;
        }
    };

    loadg(0, 0, xr0);
    loadg(0, 1, xr1);
    storeg(0, xr0);
    storeg(1, xr1);
    __syncthreads();

    for (int kc = 0; kc < 8; ++kc) {
        if (kc < 7) loadg(kc + 1, 0, xr0);

        bf16x8 av[4], bv[8];
        #pragma unroll
        for (int mt = 0; mt < 4; ++mt) {
            int sl = (kc << 2) + q;
            av[mt] = *(const bf16x8*)(wlds + (sl << 9) + ((swz((mt << 4) + m) ^ (sl & 7)) << 3));
        }
        #pragma unroll
        for (int nt = 0; nt < 8; ++nt)
            bv[nt] = *(const bf16x8*)(xTl + (q << 12) + (swz((wv << 7) + (nt << 4) + m) << 3));

        #pragma unroll
        for (int mt = 0; mt < 4; ++mt)
            #pragma unroll
            for (int nt = 0; nt < 8; ++nt)
                acc[mt][nt] = __builtin_amdgcn_mfma_f32_16x16x32_bf16(av[mt], bv[nt], acc[mt][nt], 0, 0, 0);

        if (kc < 7) loadg(kc + 1, 1, xr1);
        __syncthreads();
        if (kc < 7) {
            storeg(0, xr0);
            storeg(1, xr1);
            __syncthreads();
        }
    }

    int iv[8];
    #pragma unroll
    for (int nt = 0; nt < 8; ++nt)
        iv[nt] = idx[((size_t)b << 9) + (wv << 7) + (nt << 4) + m];

    #pragma unroll
    for (int mt = 2; mt < 4; ++mt)
        #pragma unroll
        for (int nt = 0; nt < 8; ++nt) {
            int col  = (wv << 7) + (nt << 4) + m;
            int row0 = ((mt - 2) << 4) + (q << 2);
            uint2 p;
            p.x = cvt2(acc[mt][nt][0], acc[mt][nt][1]);
            p.y = cvt2(acc[mt][nt][2], acc[mt][nt][3]);
            *(uint2*)(y2 + col * 36 + row0) = p;
        }
    __syncthreads();

    float vvl[2][8][4];
    float s_[2][4], q_[2][4];
    #pragma unroll
    for (int mt = 0; mt < 2; ++mt)
        #pragma unroll
        for (int r4 = 0; r4 < 4; ++r4) { s_[mt][r4] = 0.f; q_[mt][r4] = 0.f; }

    #pragma unroll
    for (int nt = 0; nt < 8; ++nt) {
        int  c   = iv[nt];
        bool inb = (c < 512);
        int  cc  = inb ? c : 0;
        #pragma unroll
        for (int mt = 0; mt < 2; ++mt) {
            uint2 g = *(const uint2*)(y2 + cc * 36 + (mt << 4) + (q << 2));
            float gv[4];
            gv[0] = inb ? bflo(g.x) : 0.f;
            gv[1] = inb ? bfhi(g.x) : 0.f;
            gv[2] = inb ? bflo(g.y) : 0.f;
            gv[3] = inb ? bfhi(g.y) : 0.f;
            #pragma unroll
            for (int r4 = 0; r4 < 4; ++r4) {
                float val = acc[mt][nt][r4] + gv[r4];
                vvl[mt][nt][r4] = val;
                s_[mt][r4] += val;
                q_[mt][r4] += val * val;
            }
        }
    }

    #pragma unroll
    for (int mt = 0; mt < 2; ++mt)
        #pragma unroll
        for (int r4 = 0; r4 < 4; ++r4) {
            float s = s_[mt][r4], ss = q_[mt][r4];
            #pragma unroll
            for (int off = 1; off < 16; off <<= 1) {
                s  += __shfl_xor(s,  off, 64);
                ss += __shfl_xor(ss, off, 64);
            }
            if (m == 0) {
                int r = (mt << 4) + (q << 2) + r4;
                red[(r << 3) + (wv << 1)]     = s;
                red[(r << 3) + (wv << 1) + 1] = ss;
            }
        }
    __syncthreads();

    #pragma unroll
    for (int mt = 0; mt < 2; ++mt)
        #pragma unroll
        for (int r4 = 0; r4 < 4; ++r4) {
            int r = (mt << 4) + (q << 2) + r4;
            float S = red[(r << 3)]     + red[(r << 3) + 2] + red[(r << 3) + 4] + red[(r << 3) + 6];
            float Q = red[(r << 3) + 1] + red[(r << 3) + 3] + red[(r << 3) + 5] + red[(r << 3) + 7];
            float mu  = S * (1.0f / 512.0f);
            float var = Q * (1.0f / 512.0f) - mu * mu;
            float rs  = rsqrtf(var + 1e-5f);
            float* op = out + (((size_t)(b << 8) + o0 + r) << 9) + (wv << 7) + m;
            #pragma unroll
            for (int nt = 0; nt < 8; ++nt) {
                float t = (vvl[mt][nt][r4] - mu) * rs;
                op[nt << 4] = fmaxf(t, 0.0f);
            }
        }
}

extern "C" void kernel_launch(void* const* d_in, const int* in_sizes, int n_in,
                              void* d_out, int out_size, void* d_ws, size_t ws_size,
                              hipStream_t stream) {
    const float* x   = (const float*)d_in[0];   // [256,256,512] fp32
    const int*   idx = (const int*)  d_in[1];   // [256,512] int32, 512 == pad
    const float* W   = (const float*)d_in[2];   // [256,512] fp32
    // d_in[3] (bias) unused: constant-over-L shift cancels in InstanceNorm.
    float* out = (float*)d_out;                 // [256,256,512] fp32

    const size_t xT_bytes = (size_t)256 * 32 * 512 * 8 * 2;   // 67,108,864
    const size_t wT_bytes = (size_t)8 * 32 * 64 * 8 * 2;      // 262,144

    if (ws_size >= xT_bytes + wT_bytes) {
        unsigned short* xT = (unsigned short*)d_ws;
        unsigned short* wT = (unsigned short*)((char*)d_ws + xT_bytes);
        pack_transpose<<<dim3(4104), dim3(256), 0, stream>>>(x, W, xT, wT);
        edge_gemm<<<dim3(2048), dim3(256), 0, stream>>>(xT, wT, idx, out);
    } else {
        edgeconv_fused<<<dim3(2048), dim3(256), 0, stream>>>(x, idx, W, out);
    }
}

// Round 7
// 274.432 us; speedup vs baseline: 1.8121x; 1.0714x over previous
//
#include <hip/hip_runtime.h>
#include <hip/hip_bf16.h>
#include <stdint.h>

typedef __bf16 bf16x8 __attribute__((ext_vector_type(8)));
typedef float  f32x4  __attribute__((ext_vector_type(4)));

// packed fp32x2 -> bf16x2 (RNE) -- lowers to v_cvt_pk_bf16_f32 on gfx950
__device__ __forceinline__ uint32_t cvt2(float a, float b) {
    __hip_bfloat162 h = __float22bfloat162_rn(make_float2(a, b));
    uint32_t u; __builtin_memcpy(&u, &h, 4); return u;
}
__device__ __forceinline__ float bflo(uint32_t u) { uint32_t t = u << 16;         float f; __builtin_memcpy(&f, &t, 4); return f; }
__device__ __forceinline__ float bfhi(uint32_t u) { uint32_t t = u & 0xffff0000u; float f; __builtin_memcpy(&f, &t, 4); return f; }
__device__ __forceinline__ int swz(int u) { return u ^ ((u >> 3) & 7); }

// async global -> LDS DMA, 16 B/lane. LDS dest must be wave-uniform base + lane*16.
__device__ __forceinline__ void gload_lds16(const void* g, void* l) {
    __builtin_amdgcn_global_load_lds(
        (const __attribute__((address_space(1))) uint32_t*)g,
        (__attribute__((address_space(3))) uint32_t*)l,
        16, 0, 0);
}

// ============================================================================
// Kernel 1: pack x (and W) to bf16 in MFMA-fragment-ready transposed layouts.
// (round-6 version, ~46us: 4096 x-blocks, one 256-col half each, NT loads,
// LDS-bounce swizzled stores -> contiguous 4KB-run global stores, b%8==id%8.)
// ============================================================================
__global__ __launch_bounds__(256, 4)
void pack_transpose(const float* __restrict__ x, const float* __restrict__ W,
                    unsigned short* __restrict__ xT, unsigned short* __restrict__ wT)
{
    const int tid = threadIdx.x;
    const int id  = blockIdx.x;
    if (id < 4096) {
        __shared__ __align__(16) uint4 lbuf[1024];       // 16 KB
        const int b  = ((id >> 7) << 3) + (id & 7);      // XCD-matched: b % 8 == id % 8
        const int lh = (id >> 3) & 1;                    // which 256-col half
        const int kc = (id >> 4) & 7;
        const int s2 = tid >> 6, l4 = tid & 63;          // slab-in-chunk, l-quad
        const float* src0 = x + ((size_t)b << 17) + ((size_t)((kc << 5) + (s2 << 3)) << 9);
        unsigned short* dstb = xT + (((size_t)(b << 5) + (kc << 2)) << 12);  // 4-slab base
        const int l0 = (lh << 8) + (l4 << 2);
        f32x4 xr[8];
        #pragma unroll
        for (int j = 0; j < 8; ++j)
            xr[j] = __builtin_nontemporal_load((const f32x4*)(src0 + (j << 9) + l0));
        #pragma unroll
        for (int lv = 0; lv < 4; ++lv) {
            uint4 p;
            p.x = cvt2(xr[0][lv], xr[1][lv]);
            p.y = cvt2(xr[2][lv], xr[3][lv]);
            p.z = cvt2(xr[4][lv], xr[5][lv]);
            p.w = cvt2(xr[6][lv], xr[7][lv]);
            int a = (s2 << 8) + (l4 << 2) + lv;          // slot = s2*256 + l-in-half
            lbuf[a ^ ((a >> 3) & 7)] = p;                // swizzled ds_write_b128
        }
        __syncthreads();
        #pragma unroll
        for (int i = 0; i < 4; ++i) {                    // lane t -> slot i*256+t:
            int a = (i << 8) + tid;                      // global stores 4KB-contiguous
            uint4 v = lbuf[a ^ ((a >> 3) & 7)];
            *(uint4*)(dstb + ((size_t)i << 12) + (((lh << 8) + tid) << 3)) = v;
        }
    } else {
        const int og = id - 4096;
        const int r = tid & 63, sg = tid >> 6;
        const float* wrow = W + ((size_t)((og << 5) + (r & 31)) << 9) + ((r >> 5) << 8);
        #pragma unroll
        for (int ss = 0; ss < 8; ++ss) {
            const int s = (sg << 3) + ss;
            float4 f0 = *(const float4*)(wrow + (s << 3));
            float4 f1 = *(const float4*)(wrow + (s << 3) + 4);
            uint4 p;
            p.x = cvt2(f0.x, f0.y); p.y = cvt2(f0.z, f0.w);
            p.z = cvt2(f1.x, f1.y); p.w = cvt2(f1.z, f1.w);
            *(uint4*)(wT + (((((og << 5) + s) << 6) + r) << 3)) = p;
        }
    }
}

// ============================================================================
// Kernel 2: GEMM -- ROUND-1 VERBATIM RESTORE (session-best: <=78.3us, hard
// bound from its absence in a top-5 ending at 78.28). 2-phase async-DMA LDS
// double-buffer, one __syncthreads per chunk, y2 STRIDE-36 epilogue with
// red @36864, NT out stores. The R5 "fix" (stride 34 + red@34816) regressed
// this kernel 78->89 despite killing 1M bank conflicts (VGPR 108->124,
// codegen reshuffle) -- this round A/Bs exactly that variable. Do NOT
// re-apply stride-34 without re-measuring.
// ============================================================================
__global__ __launch_bounds__(256, 2)
void edge_gemm(const unsigned short* __restrict__ xT,
               const unsigned short* __restrict__ wT,
               const int* __restrict__ idx,
               float* __restrict__ out)
{
    // buf k at smem + k*36864: B [32768 B] then A [4096 B]
    __shared__ __align__(16) unsigned char smem[73728];
    unsigned short* y2 = (unsigned short*)smem;          // bf16 [512 col][36]  (epilogue)
    float* red         = (float*)(smem + 36864);         // fp32 [32 r][4 wv][2] (epilogue)

    const int tid  = threadIdx.x;
    const int wv   = tid >> 6;
    const int lane = tid & 63;
    const int m    = lane & 15;
    const int q    = lane >> 4;

    // XCD swizzle: 8 o-blocks of one b are 8 ids apart -> same XCD round-robin
    const int id  = blockIdx.x;
    const int rem = id & 63;
    const int b   = ((id >> 6) << 3) + (rem & 7);
    const int og  = rem >> 3;
    const int o0  = og << 5;

    const char* xb = (const char*)xT + ((size_t)b << 18); // b * 256 KB
    const char* wb = (const char*)wT + (og << 15);        // og * 32 KB

    const int offS = (wv << 10) + (lane << 4);            // per-wave-linear 16B slots

    int iv[8];
    #pragma unroll
    for (int nt = 0; nt < 8; ++nt)
        iv[nt] = idx[((size_t)b << 9) + (wv << 7) + (nt << 4) + m];

    f32x4 acc[4][8];
    #pragma unroll
    for (int mt = 0; mt < 4; ++mt)
        #pragma unroll
        for (int nt = 0; nt < 8; ++nt)
            acc[mt][nt] = (f32x4){0.f, 0.f, 0.f, 0.f};

    // ---- prologue: stage chunk 0 into buf 0 (9 DMA issues/thread) ----
    {
        char* Bl = (char*)smem;
        #pragma unroll
        for (int i = 0; i < 8; ++i)
            gload_lds16(xb + (i << 12) + offS, Bl + (i << 12) + offS);
        gload_lds16(wb + offS, Bl + 32768 + offS);
    }
    __syncthreads();

    // ---- K loop: 2-phase {stage next || ds_read+MFMA current} -> drain ----
    #pragma unroll
    for (int kc = 0; kc < 8; ++kc) {
        const int cur = kc & 1;
        if (kc < 7) {
            char* Bl = (char*)smem + (cur ^ 1) * 36864;
            const char* Bg = xb + ((kc + 1) << 15);
            #pragma unroll
            for (int i = 0; i < 8; ++i)
                gload_lds16(Bg + (i << 12) + offS, Bl + (i << 12) + offS);
            gload_lds16(wb + ((kc + 1) << 12) + offS, Bl + 32768 + offS);
        }

        const unsigned short* B0 = (const unsigned short*)(smem + cur * 36864);
        const unsigned short* A0 = B0 + 16384;            // +32768 bytes
        bf16x8 av[4], bv[8];
        #pragma unroll
        for (int mt = 0; mt < 4; ++mt)
            av[mt] = *(const bf16x8*)(A0 + (q << 9) + (((mt << 4) + m) << 3));
        #pragma unroll
        for (int nt = 0; nt < 8; ++nt)
            bv[nt] = *(const bf16x8*)(B0 + (q << 12) + (((wv << 7) + (nt << 4) + m) << 3));
        #pragma unroll
        for (int mt = 0; mt < 4; ++mt)
            #pragma unroll
            for (int nt = 0; nt < 8; ++nt)
                acc[mt][nt] = __builtin_amdgcn_mfma_f32_16x16x32_bf16(av[mt], bv[nt], acc[mt][nt], 0, 0, 0);

        if (kc < 7) __syncthreads();                      // vmcnt(0)+lgkmcnt(0)+barrier
    }

    // ---- epilogue: Y2 -> LDS (bf16, transposed [col][row]); reuses buf 0,
    // which no wave touches after the kc=6 barrier ----
    #pragma unroll
    for (int mt = 2; mt < 4; ++mt)
        #pragma unroll
        for (int nt = 0; nt < 8; ++nt) {
            int col  = (wv << 7) + (nt << 4) + m;
            int row0 = ((mt - 2) << 4) + (q << 2);
            uint2 p;
            p.x = cvt2(acc[mt][nt][0], acc[mt][nt][1]);
            p.y = cvt2(acc[mt][nt][2], acc[mt][nt][3]);
            *(uint2*)(y2 + col * 36 + row0) = p;
        }
    __syncthreads();

    float vvl[2][8][4];
    float s_[2][4], q_[2][4];
    #pragma unroll
    for (int mt = 0; mt < 2; ++mt)
        #pragma unroll
        for (int r4 = 0; r4 < 4; ++r4) { s_[mt][r4] = 0.f; q_[mt][r4] = 0.f; }

    #pragma unroll
    for (int nt = 0; nt < 8; ++nt) {
        int  c   = iv[nt];
        bool inb = (c < 512);                    // idx==512 -> pad column (zero)
        int  cc  = inb ? c : 0;
        #pragma unroll
        for (int mt = 0; mt < 2; ++mt) {
            uint2 g = *(const uint2*)(y2 + cc * 36 + (mt << 4) + (q << 2));
            float gv[4];
            gv[0] = inb ? bflo(g.x) : 0.f;
            gv[1] = inb ? bfhi(g.x) : 0.f;
            gv[2] = inb ? bflo(g.y) : 0.f;
            gv[3] = inb ? bfhi(g.y) : 0.f;
            #pragma unroll
            for (int r4 = 0; r4 < 4; ++r4) {
                float val = acc[mt][nt][r4] + gv[r4];
                vvl[mt][nt][r4] = val;
                s_[mt][r4] += val;
                q_[mt][r4] += val * val;
            }
        }
    }

    // reduce: 16-lane butterfly over m, cross-wave via red (separate region)
    #pragma unroll
    for (int mt = 0; mt < 2; ++mt)
        #pragma unroll
        for (int r4 = 0; r4 < 4; ++r4) {
            float s = s_[mt][r4], ss = q_[mt][r4];
            #pragma unroll
            for (int off = 1; off < 16; off <<= 1) {
                s  += __shfl_xor(s,  off, 64);
                ss += __shfl_xor(ss, off, 64);
            }
            if (m == 0) {
                int r = (mt << 4) + (q << 2) + r4;
                red[(r << 3) + (wv << 1)]     = s;
                red[(r << 3) + (wv << 1) + 1] = ss;
            }
        }
    __syncthreads();

    #pragma unroll
    for (int mt = 0; mt < 2; ++mt)
        #pragma unroll
        for (int r4 = 0; r4 < 4; ++r4) {
            int r = (mt << 4) + (q << 2) + r4;
            float S = red[(r << 3)]     + red[(r << 3) + 2] + red[(r << 3) + 4] + red[(r << 3) + 6];
            float Q = red[(r << 3) + 1] + red[(r << 3) + 3] + red[(r << 3) + 5] + red[(r << 3) + 7];
            float mu  = S * (1.0f / 512.0f);
            float var = Q * (1.0f / 512.0f) - mu * mu;
            float rs  = rsqrtf(var + 1e-5f);
            float* op = out + (((size_t)(b << 8) + o0 + r) << 9) + (wv << 7) + m;
            #pragma unroll
            for (int nt = 0; nt < 8; ++nt) {
                float t = (vvl[mt][nt][r4] - mu) * rs;
                __builtin_nontemporal_store(fmaxf(t, 0.0f), op + (nt << 4));
            }
        }
}

// ============================================================================
// Fallback (ws too small): round-2 fused single kernel, unchanged.
// ============================================================================
__global__ __launch_bounds__(256, 2)
void edgeconv_fused(const float* __restrict__ x,
                    const int*   __restrict__ idx,
                    const float* __restrict__ W,
                    float*       __restrict__ out)
{
    __shared__ __align__(16) unsigned char smem[65536];
    unsigned short* wlds = (unsigned short*)smem;
    unsigned short* xTl  = (unsigned short*)(smem + 32768);
    unsigned short* y2   = (unsigned short*)smem;
    float*          red  = (float*)(smem + 38912);

    const int tid  = threadIdx.x;
    const int wv   = tid >> 6;
    const int lane = tid & 63;
    const int m    = lane & 15;
    const int q    = lane >> 4;

    const int id  = blockIdx.x;
    const int rem = id & 63;
    const int b   = ((id >> 6) << 3) + (rem & 7);
    const int o0  = (rem >> 3) << 5;

    const float* xb = x + ((size_t)b << 17);

    #pragma unroll
    for (int i = 0; i < 16; ++i) {
        int r = (i << 2) + wv;
        const float4 f = *(const float4*)(W + ((size_t)(o0 + (r & 31)) << 9)
                                            + ((r >> 5) << 8) + (lane << 2));
        uint2 p; p.x = cvt2(f.x, f.y); p.y = cvt2(f.z, f.w);
        int sl = lane >> 1;
        *(uint2*)(wlds + (sl << 9) + ((swz(r) ^ (sl & 7)) << 3) + ((lane & 1) << 2)) = p;
    }

    f32x4 acc[4][8];
    #pragma unroll
    for (int mt = 0; mt < 4; ++mt)
        #pragma unroll
        for (int nt = 0; nt < 8; ++nt)
            acc[mt][nt] = (f32x4){0.f, 0.f, 0.f, 0.f};

    float4 xr0[8], xr1[8];
    auto loadg = [&](int kc, int g, float4* xr) {
        int gid = (g << 8) + tid;
        int s2  = gid >> 7;
        int l4  = gid & 127;
        const float* base = xb + ((size_t)((kc << 5) + (s2 << 3)) << 9) + (l4 << 2);
        #pragma unroll
        for (int j = 0; j < 8; ++j) xr[j] = *(const float4*)(base + (j << 9));
    };
    auto storeg = [&](int g, const float4* xr) {
        int gid = (g << 8) + tid;
        int s2  = gid >> 7;
        int l4  = gid & 127;
        #pragma unroll
        for (int lv = 0; lv < 4; ++lv) {
            int l = (l4 << 2) + lv;
            uint4 p;
            p.x = cvt2((&xr[0].x)[lv], (&xr[1].x)[lv]);
            p.y = cvt2((&xr[2].x)[lv], (&xr[3].x)[lv]);
            p.z = cvt2((&xr[4].x)[lv], (&xr[5].x)[lv]);
            p.w = cvt2((&xr[6].x)[lv], (&xr[7].x)[lv]);
            *(uint4*)(xTl + (s2 << 12) + (swz(l) << 3)) = p;
        }
    };

    loadg(0, 0, xr0);
    loadg(0, 1, xr1);
    storeg(0, xr0);
    storeg(1, xr1);
    __syncthreads();

    for (int kc = 0; kc < 8; ++kc) {
        if (kc < 7) loadg(kc + 1, 0, xr0);

        bf16x8 av[4], bv[8];
        #pragma unroll
        for (int mt = 0; mt < 4; ++mt) {
            int sl = (kc << 2) + q;
            av[mt] = *(const bf16x8*)(wlds + (sl << 9) + ((swz((mt << 4) + m) ^ (sl & 7)) << 3));
        }
        #pragma unroll
        for (int nt = 0; nt < 8; ++nt)
            bv[nt] = *(const bf16x8*)(xTl + (q << 12) + (swz((wv << 7) + (nt << 4) + m) << 3));

        #pragma unroll
        for (int mt = 0; mt < 4; ++mt)
            #pragma unroll
            for (int nt = 0; nt < 8; ++nt)
                acc[mt][nt] = __builtin_amdgcn_mfma_f32_16x16x32_bf16(av[mt], bv[nt], acc[mt][nt], 0, 0, 0);

        if (kc < 7) loadg(kc + 1, 1, xr1);
        __syncthreads();
        if (kc < 7) {
            storeg(0, xr0);
            storeg(1, xr1);
            __syncthreads();
        }
    }

    int iv[8];
    #pragma unroll
    for (int nt = 0; nt < 8; ++nt)
        iv[nt] = idx[((size_t)b << 9) + (wv << 7) + (nt << 4) + m];

    #pragma unroll
    for (int mt = 2; mt < 4; ++mt)
        #pragma unroll
        for (int nt = 0; nt < 8; ++nt) {
            int col  = (wv << 7) + (nt << 4) + m;
            int row0 = ((mt - 2) << 4) + (q << 2);
            uint2 p;
            p.x = cvt2(acc[mt][nt][0], acc[mt][nt][1]);
            p.y = cvt2(acc[mt][nt][2], acc[mt][nt][3]);
            *(uint2*)(y2 + col * 36 + row0) = p;
        }
    __syncthreads();

    float vvl[2][8][4];
    float s_[2][4], q_[2][4];
    #pragma unroll
    for (int mt = 0; mt < 2; ++mt)
        #pragma unroll
        for (int r4 = 0; r4 < 4; ++r4) { s_[mt][r4] = 0.f; q_[mt][r4] = 0.f; }

    #pragma unroll
    for (int nt = 0; nt < 8; ++nt) {
        int  c   = iv[nt];
        bool inb = (c < 512);
        int  cc  = inb ? c : 0;
        #pragma unroll
        for (int mt = 0; mt < 2; ++mt) {
            uint2 g = *(const uint2*)(y2 + cc * 36 + (mt << 4) + (q << 2));
            float gv[4];
            gv[0] = inb ? bflo(g.x) : 0.f;
            gv[1] = inb ? bfhi(g.x) : 0.f;
            gv[2] = inb ? bflo(g.y) : 0.f;
            gv[3] = inb ? bfhi(g.y) : 0.f;
            #pragma unroll
            for (int r4 = 0; r4 < 4; ++r4) {
                float val = acc[mt][nt][r4] + gv[r4];
                vvl[mt][nt][r4] = val;
                s_[mt][r4] += val;
                q_[mt][r4] += val * val;
            }
        }
    }

    #pragma unroll
    for (int mt = 0; mt < 2; ++mt)
        #pragma unroll
        for (int r4 = 0; r4 < 4; ++r4) {
            float s = s_[mt][r4], ss = q_[mt][r4];
            #pragma unroll
            for (int off = 1; off < 16; off <<= 1) {
                s  += __shfl_xor(s,  off, 64);
                ss += __shfl_xor(ss, off, 64);
            }
            if (m == 0) {
                int r = (mt << 4) + (q << 2) + r4;
                red[(r << 3) + (wv << 1)]     = s;
                red[(r << 3) + (wv << 1) + 1] = ss;
            }
        }
    __syncthreads();

    #pragma unroll
    for (int mt = 0; mt < 2; ++mt)
        #pragma unroll
        for (int r4 = 0; r4 < 4; ++r4) {
            int r = (mt << 4) + (q << 2) + r4;
            float S = red[(r << 3)]     + red[(r << 3) + 2] + red[(r << 3) + 4] + red[(r << 3) + 6];
            float Q = red[(r << 3) + 1] + red[(r << 3) + 3] + red[(r << 3) + 5] + red[(r << 3) + 7];
            float mu  = S * (1.0f / 512.0f);
            float var = Q * (1.0f / 512.0f) - mu * mu;
            float rs  = rsqrtf(var + 1e-5f);
            float* op = out + (((size_t)(b << 8) + o0 + r) << 9) + (wv << 7) + m;
            #pragma unroll
            for (int nt = 0; nt < 8; ++nt) {
                float t = (vvl[mt][nt][r4] - mu) * rs;
                op[nt << 4] = fmaxf(t, 0.0f);
            }
        }
}

extern "C" void kernel_launch(void* const* d_in, const int* in_sizes, int n_in,
                              void* d_out, int out_size, void* d_ws, size_t ws_size,
                              hipStream_t stream) {
    const float* x   = (const float*)d_in[0];   // [256,256,512] fp32
    const int*   idx = (const int*)  d_in[1];   // [256,512] int32, 512 == pad
    const float* W   = (const float*)d_in[2];   // [256,512] fp32
    // d_in[3] (bias) unused: constant-over-L shift cancels in InstanceNorm.
    float* out = (float*)d_out;                 // [256,256,512] fp32

    const size_t xT_bytes = (size_t)256 * 32 * 512 * 8 * 2;   // 67,108,864
    const size_t wT_bytes = (size_t)8 * 32 * 64 * 8 * 2;      // 262,144

    if (ws_size >= xT_bytes + wT_bytes) {
        unsigned short* xT = (unsigned short*)d_ws;
        unsigned short* wT = (unsigned short*)((char*)d_ws + xT_bytes);
        pack_transpose<<<dim3(4104), dim3(256), 0, stream>>>(x, W, xT, wT);
        edge_gemm<<<dim3(2048), dim3(256), 0, stream>>>(xT, wT, idx, out);
    } else {
        edgeconv_fused<<<dim3(2048), dim3(256), 0, stream>>>(x, idx, W, out);
    }
}